// Round 11
// baseline (969.993 us; speedup 1.0000x reference)
//
#include <hip/hip_runtime.h>
#include <math.h>

#define H 128
#define NCLS 10
#define EPS 1e-5f
#define BN_BETA 1e-4f
#define CS_BLOCKS 256

typedef unsigned short u16;
typedef unsigned int u32;
typedef __attribute__((ext_vector_type(8))) short short8;
typedef __attribute__((ext_vector_type(4))) float floatx4;

// ---- bf16 helpers (bit ops; RNE) ----
__device__ inline float bflo(u32 u) { union { u32 i; float f; } a; a.i = u << 16; return a.f; }
__device__ inline float bfhi(u32 u) { union { u32 i; float f; } a; a.i = u & 0xffff0000u; return a.f; }
__device__ inline u16 f2bf(float f) {
  union { float f; u32 i; } v; v.f = f;
  return (u16)((v.i + 0x7fff + ((v.i >> 16) & 1)) >> 16);
}
__device__ inline u32 pack2(float a, float b) { return (u32)f2bf(a) | ((u32)f2bf(b) << 16); }

// ---- latency-tolerant partial-row reduction: 8 independent streams ----------
__device__ inline void reduce_partials(const float* __restrict__ P, int nb, int stride,
                                       int off0, int f, float* su_out, float* sq_out) {
  float su[8] = {0, 0, 0, 0, 0, 0, 0, 0}, sq[8] = {0, 0, 0, 0, 0, 0, 0, 0};
  int b = 0;
  for (; b + 8 <= nb; b += 8) {
#pragma unroll
    for (int u = 0; u < 8; u++) {
      const float* p = P + (size_t)(b + u) * stride + off0;
      su[u] += p[f];
      sq[u] += p[128 + f];
    }
  }
  for (; b < nb; b++) {
    const float* p = P + (size_t)b * stride + off0;
    su[0] += p[f];
    sq[0] += p[128 + f];
  }
  *su_out = ((su[0] + su[1]) + (su[2] + su[3])) + ((su[4] + su[5]) + (su[6] + su[7]));
  *sq_out = ((sq[0] + sq[1]) + (sq[2] + sq[3])) + ((sq[4] + sq[5]) + (sq[6] + sq[7]));
}

// ================= x stats (fp32 input, stats only, no atomics) ==============
__global__ __launch_bounds__(256) void xstats_kernel(
    const float* __restrict__ x, int n4, float* __restrict__ stp) {
  int tid = threadIdx.x;
  int lane = tid & 63, wave = tid >> 6;
  float s[4] = {0, 0, 0, 0}, q[4] = {0, 0, 0, 0};
  int step = gridDim.x * 256;
  for (int i = blockIdx.x * 256 + tid; i < n4; i += step) {
    float4 v = ((const float4*)x)[i];
    s[0] += v.x; q[0] += v.x * v.x; s[1] += v.y; q[1] += v.y * v.y;
    s[2] += v.z; q[2] += v.z * v.z; s[3] += v.w; q[3] += v.w * v.w;
  }
#pragma unroll
  for (int k = 0; k < 4; k++) { s[k] += __shfl_xor(s[k], 32); q[k] += __shfl_xor(q[k], 32); }
  __shared__ float sm[4][256];
  int col = (lane & 31) * 4;
  if (lane < 32) {
#pragma unroll
    for (int k = 0; k < 4; k++) { sm[wave][col + k] = s[k]; sm[wave][128 + col + k] = q[k]; }
  }
  __syncthreads();
  stp[(size_t)blockIdx.x * 256 + tid] = sm[0][tid] + sm[1][tid] + sm[2][tid] + sm[3][tid];
}

// ================= fold: reduce partials + BN-fold into Wt (bf16,T) ==========
__device__ inline void fold_body(const float* P, int nb, int stride, int off0,
                                 const float* W, const float* bias,
                                 float invN, int k, u16* Wt, float* cf) {
  int f = threadIdx.x;
  float su, sq;
  reduce_partials(P, nb, stride, off0, f, &su, &sq);
  float mu = su * invN;
  float var = sq * invN - mu * mu;
  float s = 1.0f / sqrtf(fmaxf(var, 0.f) + EPS);
  float w = W[(size_t)f * H + k];
  Wt[(size_t)k * H + f] = f2bf(s * w);
  __shared__ float red[H];
  red[f] = (BN_BETA - mu * s) * w;
  __syncthreads();
  for (int o = 64; o > 0; o >>= 1) {
    if (f < o) red[f] += red[f + o];
    __syncthreads();
  }
  if (f == 0) cf[k] = red[0] + (bias ? bias[k] : 0.f);
}

__global__ __launch_bounds__(128) void fold_kernel(
    const float* P, int nb, const float* W, const float* bias, float invN,
    u16* Wt, float* cf) {
  fold_body(P, nb, 256, 0, W, bias, invN, blockIdx.x, Wt, cf);
}

// ctx+obj: stats from stpPre (row=512: [c_s|c_q|o_s|o_q]); cf = cvec.W only
__global__ __launch_bounds__(128) void fold2_kernel(
    const float* P, int nb, const float* W0, const float* W1, float invN,
    u16* Wt2, float* cf2) {
  int j = blockIdx.x >> 7, k = blockIdx.x & 127;
  fold_body(P, nb, 512, j * 256, j ? W1 : W0, nullptr, invN, k,
            Wt2 + (size_t)j * H * H, cf2 + j * H);
}

// fc1 x3: per-head stats source/nb
__global__ __launch_bounds__(128) void fold3_kernel(
    const float* PC, int nbC, const float* PO, int nbO, const float* PCO, int nbCO,
    const float* W_fc1, const float* b_fc1, float invN, u16* Wt3, float* cf3) {
  int j = blockIdx.x >> 7, k = blockIdx.x & 127;
  const float* P = (j == 0) ? PC : (j == 1) ? PO : PCO;
  int nb = (j == 0) ? nbC : (j == 1) ? nbO : nbCO;
  fold_body(P, nb, 256, 0, W_fc1 + (size_t)j * H * H, b_fc1 + j * H, invN, k,
            Wt3 + (size_t)j * H * H, cf3 + j * H);
}

// fc2 x3 (Kout=10, fp32 out)
__global__ __launch_bounds__(128) void fold10x3_kernel(
    const float* stpZ, int nb, const float* W_fc2, const float* b_fc2, float invN,
    float* W2f, float* c2f) {
  int j = blockIdx.x / NCLS, k = blockIdx.x % NCLS;
  const float* P = stpZ + (size_t)j * nb * 256;
  int f = threadIdx.x;
  float su, sq;
  reduce_partials(P, nb, 256, 0, f, &su, &sq);
  float mu = su * invN;
  float var = sq * invN - mu * mu;
  float s = 1.0f / sqrtf(fmaxf(var, 0.f) + EPS);
  float w = W_fc2[(size_t)j * H * NCLS + (size_t)f * NCLS + k];
  W2f[(size_t)j * H * NCLS + (size_t)f * NCLS + k] = s * w;
  __shared__ float red[H];
  red[f] = (BN_BETA - mu * s) * w;
  __syncthreads();
  for (int o = 64; o > 0; o >>= 1) {
    if (f < o) red[f] += red[f + o];
    __syncthreads();
  }
  if (f == 0) c2f[j * 16 + k] = red[0] + b_fc2[j * NCLS + k];
}

// ================= bf16 MFMA GEMM core (optionally fp32 A, sumw, stats) ======
__device__ inline void gemm_core(const u16* A, const float* Afp, const u16* Bt,
                                 const float* cf, const float* b2, const float* sumw,
                                 u16* C, int N, int relu, int blk, float* stp) {
  int tid = threadIdx.x;
  int wave = tid >> 6, lane = tid & 63;
  int l15 = lane & 15, quad = lane >> 4;
  int row0 = (blk * 4 + wave) * 16;
  if (row0 >= N && !stp) return;
  int arow = row0 + l15;
  short8 a[4];
  short8 z8 = {0, 0, 0, 0, 0, 0, 0, 0};
  if (Afp) {
#pragma unroll
    for (int k4 = 0; k4 < 4; k4++) {
      if (arow < N) {
        const float* p = Afp + (size_t)arow * H + k4 * 32 + quad * 8;
        float4 f0 = *(const float4*)p;
        float4 f1 = *(const float4*)(p + 4);
        union { short8 s8; u32 u[4]; } cv;
        cv.u[0] = pack2(f0.x, f0.y); cv.u[1] = pack2(f0.z, f0.w);
        cv.u[2] = pack2(f1.x, f1.y); cv.u[3] = pack2(f1.z, f1.w);
        a[k4] = cv.s8;
      } else a[k4] = z8;
    }
  } else {
#pragma unroll
    for (int k4 = 0; k4 < 4; k4++)
      a[k4] = (arow < N) ? *(const short8*)(A + (size_t)arow * H + k4 * 32 + quad * 8) : z8;
  }
  float srow[4];
  if (sumw) {
#pragma unroll
    for (int r = 0; r < 4; r++) {
      int row = row0 + quad * 4 + r;
      srow[r] = (row < N) ? sumw[row] : 0.f;
    }
  }
  float ps[8], pq[8];
#pragma unroll
  for (int nt = 0; nt < 8; nt++) {
    floatx4 acc = {0.f, 0.f, 0.f, 0.f};
    const u16* bp = Bt + (size_t)(nt * 16 + l15) * H + quad * 8;
#pragma unroll
    for (int k4 = 0; k4 < 4; k4++) {
      short8 b = *(const short8*)(bp + k4 * 32);
      acc = __builtin_amdgcn_mfma_f32_16x16x32_bf16(a[k4], b, acc, 0, 0, 0);
    }
    int col = nt * 16 + l15;
    float base = cf[col];
    float bb = b2 ? b2[col] : 0.f;
    float s_ = 0.f, q_ = 0.f;
#pragma unroll
    for (int r = 0; r < 4; r++) {
      int row = row0 + quad * 4 + r;
      if (row < N) {
        float v = acc[r] + (sumw ? srow[r] * base + bb : base);
        if (relu) v = fmaxf(v, 0.f);
        s_ += v; q_ += v * v;
        C[(size_t)row * H + col] = f2bf(v);
      }
    }
    ps[nt] = s_; pq[nt] = q_;
  }
  if (stp) {
    __shared__ float sred[4][256];
#pragma unroll
    for (int nt = 0; nt < 8; nt++) {
      ps[nt] += __shfl_xor(ps[nt], 16); ps[nt] += __shfl_xor(ps[nt], 32);
      pq[nt] += __shfl_xor(pq[nt], 16); pq[nt] += __shfl_xor(pq[nt], 32);
    }
    if (quad == 0) {
#pragma unroll
      for (int nt = 0; nt < 8; nt++) {
        sred[wave][nt * 16 + l15] = ps[nt];
        sred[wave][128 + nt * 16 + l15] = pq[nt];
      }
    }
    __syncthreads();
    stp[(size_t)blk * 256 + tid] =
        sred[0][tid] + sred[1][tid] + sred[2][tid] + sred[3][tid];
  }
}

__global__ __launch_bounds__(256) void gemm_x_kernel(
    const float* x, const u16* Bt, const float* cf, u16* C, int N, float* stp) {
  gemm_core(nullptr, x, Bt, cf, nullptr, nullptr, C, N, 1, blockIdx.x, stp);
}

// conv: h_next = relu(g.Wt + sumw[row]*cf[col] + b[col]), stats epilogue
__global__ __launch_bounds__(256) void gemmsw_kernel(
    const u16* G, const u16* Wt, const float* cf, const float* b2,
    const float* sumw, u16* C, int N, float* stp) {
  gemm_core(G, nullptr, Wt, cf, b2, sumw, C, N, 1, blockIdx.x, stp);
}

// ctx/obj: in-place, v = relu(acc + sumw[row]*cf[col] + b[col]), stats
__global__ __launch_bounds__(256) void gemm2sw_kernel(
    u16* B0, u16* B1, const u16* Wt2, const float* cf2,
    const float* b0, const float* b1, const float* sw0, const float* sw1,
    int N, int gG, float* stp) {
  int j = blockIdx.x / gG, blk = blockIdx.x % gG;
  u16* Z = j ? B1 : B0;
  gemm_core(Z, nullptr, Wt2 + (size_t)j * H * H, cf2 + j * H, j ? b1 : b0,
            j ? sw1 : sw0, Z, N, 1, blk, stp + (size_t)j * gG * 256);
}

// fc1 x3: in-place, relu, stats
__global__ __launch_bounds__(256) void gemm3_kernel(
    u16* Z0, u16* Z1, u16* Z2, const u16* Wt3, const float* cf3,
    int N, int gG, float* stp) {
  int j = blockIdx.x / gG, blk = blockIdx.x % gG;
  u16* Z = (j == 0) ? Z0 : (j == 1) ? Z1 : Z2;
  gemm_core(Z, nullptr, Wt3 + (size_t)j * H * H, cf3 + j * H, nullptr, nullptr,
            Z, N, 1, blk, stp + (size_t)j * gG * 256);
}

// ================= CSR build =================
__global__ __launch_bounds__(256) void hist_kernel(
    const int* __restrict__ row, const int* __restrict__ col, int E,
    int* __restrict__ cnt, float* __restrict__ deg) {
  int e = blockIdx.x * 256 + threadIdx.x;
  if (e < E) {
    atomicAdd(&cnt[col[e]], 1);
    atomicAdd(&deg[row[e]], 1.0f);
  }
}

__global__ __launch_bounds__(256) void scanA_rsqrt_kernel(
    const int* __restrict__ cnt, const float* __restrict__ deg, int N,
    int* __restrict__ partial, float* __restrict__ dinv) {
  int i = blockIdx.x * 256 + threadIdx.x;
  if (i < N) dinv[i] = 1.0f / sqrtf(deg[i] + 1.0f);
  __shared__ int sd[256];
  sd[threadIdx.x] = (i < N) ? cnt[i] : 0;
  __syncthreads();
  for (int o = 128; o > 0; o >>= 1) {
    if (threadIdx.x < o) sd[threadIdx.x] += sd[threadIdx.x + o];
    __syncthreads();
  }
  if (threadIdx.x == 0) partial[blockIdx.x] = sd[0];
}

__global__ __launch_bounds__(256) void scanB_kernel(const int* __restrict__ partial, int nb,
                                                    int* __restrict__ blockoff) {
  __shared__ int sd[256];
  int t = threadIdx.x;
  int v = (t < nb) ? partial[t] : 0;
  sd[t] = v;
  __syncthreads();
  for (int o = 1; o < 256; o <<= 1) {
    int x = (t >= o) ? sd[t - o] : 0;
    __syncthreads();
    sd[t] += x;
    __syncthreads();
  }
  blockoff[t] = sd[t] - v;
}

__global__ __launch_bounds__(256) void scanC_kernel(
    const int* __restrict__ cnt, int N, const int* __restrict__ blockoff,
    int* __restrict__ off, int* __restrict__ cur, int E) {
  __shared__ int sd[256];
  int t = threadIdx.x;
  int i = blockIdx.x * 256 + t;
  int v = (i < N) ? cnt[i] : 0;
  sd[t] = v;
  __syncthreads();
  for (int o = 1; o < 256; o <<= 1) {
    int x = (t >= o) ? sd[t - o] : 0;
    __syncthreads();
    sd[t] += x;
    __syncthreads();
  }
  if (i < N) {
    int ex = blockoff[blockIdx.x] + sd[t] - v;
    off[i] = ex;
    cur[i] = ex;
  }
  if (i == 0) off[N] = E;
}

__global__ __launch_bounds__(256) void place_kernel(
    const int* __restrict__ row, const int* __restrict__ col, int E,
    int* __restrict__ cur, const float* __restrict__ dinv,
    int* __restrict__ csr_src, int* __restrict__ slot_of, float* __restrict__ wn) {
  int e = blockIdx.x * 256 + threadIdx.x;
  if (e < E) {
    int r = row[e];
    int slot = atomicAdd(&cur[col[e]], 1);
    csr_src[slot] = r;
    slot_of[e] = slot;
    wn[slot] = dinv[r];
  }
}

__global__ __launch_bounds__(256) void rsqrt2_kernel(
    const float* __restrict__ deg, const float* __restrict__ degc,
    float* __restrict__ dinvc, float* __restrict__ dinvo, int N) {
  int v = blockIdx.x * 256 + threadIdx.x;
  if (v < N) {
    float dc = degc[v];
    dinvc[v] = 1.0f / sqrtf(dc + 1.0f);
    dinvo[v] = 1.0f / sqrtf(deg[v] - dc + 1.0f);
  }
}

// per-slot packed weights: wfa = {a0*dinvc[s]*na0[s], (1-a0)*dinvo[s]*na1[s]},
// wfr = {a0*dinvc[s], (1-a0)*dinvo[s]}
__global__ __launch_bounds__(256) void wa2_kernel(
    const int* csr_src, const float* att0s, const float* dinvc, const float* dinvo,
    const float2* na01, float2* wfa, float2* wfr, int E) {
  int i = blockIdx.x * 256 + threadIdx.x;
  if (i >= E) return;
  int s = csr_src[i];
  float a0 = att0s[i];
  float2 na = na01[s];
  float r0 = a0 * dinvc[s];
  float r1 = (1.0f - a0) * dinvo[s];
  wfa[i] = make_float2(r0 * na.x, r1 * na.y);
  wfr[i] = make_float2(r0, r1);
}

// ================= conv aggregation over h (raw, no relu/bias) ===============
#define ACC8(A, U, W)                                             \
  A[0] += (W) * bflo(U.x); A[1] += (W) * bfhi(U.x);               \
  A[2] += (W) * bflo(U.y); A[3] += (W) * bfhi(U.y);               \
  A[4] += (W) * bflo(U.z); A[5] += (W) * bfhi(U.z);               \
  A[6] += (W) * bflo(U.w); A[7] += (W) * bfhi(U.w);

__global__ __launch_bounds__(256) void aggn_kernel(
    const u16* __restrict__ h, const int* __restrict__ csr_src,
    const float* __restrict__ wn, const int* __restrict__ off,
    const float* __restrict__ dinv, u16* __restrict__ gout,
    float* __restrict__ sumw, int N) {
  int v = blockIdx.x * 4 + (threadIdx.x >> 6);
  if (v >= N) return;
  int lane = threadIdx.x & 63;
  int g = lane >> 4, li = lane & 15;
  const uint4* T = (const uint4*)h;
  float dv = dinv[v];
  float acc[8] = {0.f, 0.f, 0.f, 0.f, 0.f, 0.f, 0.f, 0.f};
  float sw = 0.f;
  if (g == 0) {
    uint4 u = T[(size_t)v * 16 + li];
    float w0 = dv * dv;
    ACC8(acc, u, w0)
  }
  int s0 = off[v], s1 = off[v + 1];
  for (int s = s0; s < s1; s += 32) {
    int ix[8]; float wv[8];
#pragma unroll
    for (int u = 0; u < 8; u++) {
      int e = s + g + u * 4;
      bool ok = e < s1;
      int e2 = ok ? e : s0;
      ix[u] = csr_src[e2];
      wv[u] = ok ? wn[e2] : 0.f;
    }
    uint4 uu[8];
#pragma unroll
    for (int u = 0; u < 8; u++) uu[u] = T[(size_t)ix[u] * 16 + li];
#pragma unroll
    for (int u = 0; u < 8; u++) { float w = wv[u] * dv; ACC8(acc, uu[u], w) sw += wv[u]; }
  }
#pragma unroll
  for (int j = 0; j < 8; j++) {
    acc[j] += __shfl_xor(acc[j], 16);
    acc[j] += __shfl_xor(acc[j], 32);
  }
  sw += __shfl_xor(sw, 16); sw += __shfl_xor(sw, 32);
  if (g == 0) {
    uint4 w4;
    w4.x = pack2(acc[0], acc[1]); w4.y = pack2(acc[2], acc[3]);
    w4.z = pack2(acc[4], acc[5]); w4.w = pack2(acc[6], acc[7]);
    ((uint4*)gout)[(size_t)v * 16 + li] = w4;
    if (sumw && li == 0) sumw[v] = dv * sw + dv * dv;
  }
}

// ---- dual aggregation over shared table h (ctx + obj), + sumw accumulators ----
__global__ __launch_bounds__(256) void aggdual_kernel(
    const u16* __restrict__ h, const int* __restrict__ csr_src,
    const float2* __restrict__ wfa, const float2* __restrict__ wfr,
    const int* __restrict__ off, const float* __restrict__ dinvc,
    const float* __restrict__ dinvo, const float2* __restrict__ na01,
    u16* __restrict__ gc, u16* __restrict__ go,
    float* __restrict__ sumw_c, float* __restrict__ sumw_o, int N) {
  int v = blockIdx.x * 4 + (threadIdx.x >> 6);
  if (v >= N) return;
  int lane = threadIdx.x & 63;
  int g = lane >> 4, li = lane & 15;
  const uint4* T = (const uint4*)h;
  float dvc = dinvc[v], dvo = dinvo[v];
  float ac[8] = {0.f, 0.f, 0.f, 0.f, 0.f, 0.f, 0.f, 0.f};
  float ao[8] = {0.f, 0.f, 0.f, 0.f, 0.f, 0.f, 0.f, 0.f};
  float swc = 0.f, swo = 0.f;
  if (g == 0) {
    uint4 u = T[(size_t)v * 16 + li];
    float2 na = na01[v];
    float wc = dvc * dvc, wo = dvo * dvo;
    float wch = wc * na.x, woh = wo * na.y;
    ACC8(ac, u, wch)
    ACC8(ao, u, woh)
  }
  int s0 = off[v], s1 = off[v + 1];
  for (int s = s0; s < s1; s += 16) {
    int ix[4]; float2 fa[4], fr[4];
#pragma unroll
    for (int u = 0; u < 4; u++) {
      int e = s + g + u * 4;
      bool ok = e < s1;
      int e2 = ok ? e : s0;
      ix[u] = csr_src[e2];
      fa[u] = ok ? wfa[e2] : make_float2(0.f, 0.f);
      fr[u] = ok ? wfr[e2] : make_float2(0.f, 0.f);
    }
    uint4 uu[4];
#pragma unroll
    for (int u = 0; u < 4; u++) uu[u] = T[(size_t)ix[u] * 16 + li];
#pragma unroll
    for (int u = 0; u < 4; u++) {
      float wc = fa[u].x * dvc; ACC8(ac, uu[u], wc)
      float wo = fa[u].y * dvo; ACC8(ao, uu[u], wo)
      swc += fr[u].x; swo += fr[u].y;
    }
  }
#pragma unroll
  for (int j = 0; j < 8; j++) {
    ac[j] += __shfl_xor(ac[j], 16); ac[j] += __shfl_xor(ac[j], 32);
    ao[j] += __shfl_xor(ao[j], 16); ao[j] += __shfl_xor(ao[j], 32);
  }
  swc += __shfl_xor(swc, 16); swc += __shfl_xor(swc, 32);
  swo += __shfl_xor(swo, 16); swo += __shfl_xor(swo, 32);
  if (g == 0) {
    uint4 wc4, wo4;
    wc4.x = pack2(ac[0], ac[1]); wc4.y = pack2(ac[2], ac[3]);
    wc4.z = pack2(ac[4], ac[5]); wc4.w = pack2(ac[6], ac[7]);
    wo4.x = pack2(ao[0], ao[1]); wo4.y = pack2(ao[2], ao[3]);
    wo4.z = pack2(ao[4], ao[5]); wo4.w = pack2(ao[6], ao[7]);
    ((uint4*)gc)[(size_t)v * 16 + li] = wc4;
    ((uint4*)go)[(size_t)v * 16 + li] = wo4;
    if (li == 0) {
      sumw_c[v] = dvc * swc + dvc * dvc;
      sumw_o[v] = dvo * swo + dvo * dvo;
    }
  }
}

// ================= node attention + edge-att p,q factors =====================
__global__ __launch_bounds__(256) void natt_kernel(
    const u16* __restrict__ h, int N,
    const float* __restrict__ W_na, const float* __restrict__ b_na,
    const float* __restrict__ W_ea,
    float2* __restrict__ na01, float2* __restrict__ p01, float2* __restrict__ q01) {
  int n = blockIdx.x * 256 + threadIdx.x;
  if (n >= N) return;
  float sa0 = 0, sa1 = 0, sp0 = 0, sp1 = 0, sq0 = 0, sq1 = 0;
  const uint2* hr = (const uint2*)(h + (size_t)n * H);
  for (int c = 0; c < 32; c++) {
    uint2 u = hr[c];
    float v0 = bflo(u.x), v1 = bfhi(u.x), v2 = bflo(u.y), v3 = bfhi(u.y);
    int k = c * 4;
    sa0 += v0 * W_na[k * 2] + v1 * W_na[k * 2 + 2] + v2 * W_na[k * 2 + 4] + v3 * W_na[k * 2 + 6];
    sa1 += v0 * W_na[k * 2 + 1] + v1 * W_na[k * 2 + 3] + v2 * W_na[k * 2 + 5] + v3 * W_na[k * 2 + 7];
    sp0 += v0 * W_ea[k * 2] + v1 * W_ea[k * 2 + 2] + v2 * W_ea[k * 2 + 4] + v3 * W_ea[k * 2 + 6];
    sp1 += v0 * W_ea[k * 2 + 1] + v1 * W_ea[k * 2 + 3] + v2 * W_ea[k * 2 + 5] + v3 * W_ea[k * 2 + 7];
    sq0 += v0 * W_ea[(H + k) * 2] + v1 * W_ea[(H + k) * 2 + 2] + v2 * W_ea[(H + k) * 2 + 4] + v3 * W_ea[(H + k) * 2 + 6];
    sq1 += v0 * W_ea[(H + k) * 2 + 1] + v1 * W_ea[(H + k) * 2 + 3] + v2 * W_ea[(H + k) * 2 + 5] + v3 * W_ea[(H + k) * 2 + 7];
  }
  sa0 += b_na[0]; sa1 += b_na[1];
  float m = fmaxf(sa0, sa1);
  float e0 = expf(sa0 - m), e1 = expf(sa1 - m);
  float inv = 1.f / (e0 + e1);
  na01[n] = make_float2(e0 * inv, e1 * inv);
  p01[n] = make_float2(sp0, sp1);
  q01[n] = make_float2(sq0, sq1);
}

// ================= stats of na0*h, na1*h (NOT materialized) ==================
__global__ __launch_bounds__(256) void xprestats_kernel(
    const u16* __restrict__ h, const float2* __restrict__ na01, int n4,
    float* __restrict__ stp) {
  int tid = threadIdx.x;
  int lane = tid & 63, wave = tid >> 6;
  float sc[4] = {0, 0, 0, 0}, qc[4] = {0, 0, 0, 0};
  float so[4] = {0, 0, 0, 0}, qo[4] = {0, 0, 0, 0};
  int step = gridDim.x * 256;
  for (int i = blockIdx.x * 256 + tid; i < n4; i += step) {
    int n = i >> 5;
    uint2 u = ((const uint2*)h)[i];
    float v0 = bflo(u.x), v1 = bfhi(u.x), v2 = bflo(u.y), v3 = bfhi(u.y);
    float2 ab = na01[n];
    float a = ab.x, b = ab.y;
    float c0 = v0 * a, c1 = v1 * a, c2 = v2 * a, c3 = v3 * a;
    float o0 = v0 * b, o1 = v1 * b, o2 = v2 * b, o3 = v3 * b;
    sc[0] += c0; qc[0] += c0 * c0; sc[1] += c1; qc[1] += c1 * c1;
    sc[2] += c2; qc[2] += c2 * c2; sc[3] += c3; qc[3] += c3 * c3;
    so[0] += o0; qo[0] += o0 * o0; so[1] += o1; qo[1] += o1 * o1;
    so[2] += o2; qo[2] += o2 * o2; so[3] += o3; qo[3] += o3 * o3;
  }
#pragma unroll
  for (int k = 0; k < 4; k++) {
    sc[k] += __shfl_xor(sc[k], 32); qc[k] += __shfl_xor(qc[k], 32);
    so[k] += __shfl_xor(so[k], 32); qo[k] += __shfl_xor(qo[k], 32);
  }
  __shared__ float sm[4][512];
  int col = (lane & 31) * 4;
  if (lane < 32) {
#pragma unroll
    for (int k = 0; k < 4; k++) {
      sm[wave][col + k] = sc[k];
      sm[wave][128 + col + k] = qc[k];
      sm[wave][256 + col + k] = so[k];
      sm[wave][384 + col + k] = qo[k];
    }
  }
  __syncthreads();
  float r0 = sm[0][tid] + sm[1][tid] + sm[2][tid] + sm[3][tid];
  float r1 = sm[0][256 + tid] + sm[1][256 + tid] + sm[2][256 + tid] + sm[3][256 + tid];
  stp[(size_t)blockIdx.x * 512 + tid] = r0;
  stp[(size_t)blockIdx.x * 512 + 256 + tid] = r1;
}

// ================= edge attention -> CSR-order att0 + degc ===================
__global__ __launch_bounds__(256) void eatt_kernel(
    const int* __restrict__ row, const int* __restrict__ col, int E,
    const float2* __restrict__ p01, const float2* __restrict__ q01,
    const float* __restrict__ b_ea, const int* __restrict__ slot_of,
    float* __restrict__ att0s, float* __restrict__ degc) {
  int e = blockIdx.x * 256 + threadIdx.x;
  if (e >= E) return;
  int r = row[e], c = col[e];
  float2 p = p01[r], q = q01[c];
  float l0 = p.x + q.x + b_ea[0];
  float l1 = p.y + q.y + b_ea[1];
  float a0 = 1.0f / (1.0f + expf(l1 - l0));
  att0s[slot_of[e]] = a0;
  atomicAdd(&degc[r], a0);
}

// ================= h_co = xc[perm] + xo, fused stats =========================
__global__ __launch_bounds__(256) void permadd_stats_kernel(
    const u16* __restrict__ xc, const u16* __restrict__ xo,
    const int* __restrict__ perm, u16* __restrict__ out, int n4, float* __restrict__ stp) {
  int tid = threadIdx.x;
  int lane = tid & 63, wave = tid >> 6;
  float s[4] = {0, 0, 0, 0}, q[4] = {0, 0, 0, 0};
  int step = gridDim.x * 256;
  for (int i = blockIdx.x * 256 + tid; i < n4; i += step) {
    int n = i >> 5, k = i & 31;
    int p = perm[n];
    uint2 a = ((const uint2*)xc)[(size_t)p * 32 + k];
    uint2 b = ((const uint2*)xo)[i];
    float f0 = bflo(a.x) + bflo(b.x), f1 = bfhi(a.x) + bfhi(b.x);
    float f2 = bflo(a.y) + bflo(b.y), f3 = bfhi(a.y) + bfhi(b.y);
    ((uint2*)out)[i] = make_uint2(pack2(f0, f1), pack2(f2, f3));
    s[0] += f0; q[0] += f0 * f0; s[1] += f1; q[1] += f1 * f1;
    s[2] += f2; q[2] += f2 * f2; s[3] += f3; q[3] += f3 * f3;
  }
#pragma unroll
  for (int k = 0; k < 4; k++) { s[k] += __shfl_xor(s[k], 32); q[k] += __shfl_xor(q[k], 32); }
  __shared__ float sm[4][256];
  int col = (lane & 31) * 4;
  if (lane < 32) {
#pragma unroll
    for (int k = 0; k < 4; k++) { sm[wave][col + k] = s[k]; sm[wave][128 + col + k] = q[k]; }
  }
  __syncthreads();
  stp[(size_t)blockIdx.x * 256 + tid] = sm[0][tid] + sm[1][tid] + sm[2][tid] + sm[3][tid];
}

// ================= fc2 x3: [N,128]@[128,10] + log_softmax ====================
__global__ __launch_bounds__(256) void fc2x3_kernel(
    const u16* __restrict__ z0, const u16* __restrict__ z1, const u16* __restrict__ z2,
    const float* __restrict__ W2f, const float* __restrict__ c2f,
    float* __restrict__ outp, int N, int gN) {
  int j = blockIdx.x / gN, blk = blockIdx.x % gN;
  int n = blk * 256 + threadIdx.x;
  if (n >= N) return;
  const u16* z = (j == 0) ? z0 : (j == 1) ? z1 : z2;
  const float* W2 = W2f + (size_t)j * H * NCLS;
  const float* c2 = c2f + j * 16;
  float* op = outp + (size_t)j * N * NCLS;
  float acc[NCLS];
#pragma unroll
  for (int c = 0; c < NCLS; c++) acc[c] = c2[c];
  const uint2* zr = (const uint2*)(z + (size_t)n * H);
  for (int c4 = 0; c4 < 32; c4++) {
    uint2 u = zr[c4];
    float v[4] = {bflo(u.x), bfhi(u.x), bflo(u.y), bfhi(u.y)};
    int k = c4 * 4;
#pragma unroll
    for (int jj = 0; jj < 4; jj++)
#pragma unroll
      for (int c = 0; c < NCLS; c++) acc[c] += v[jj] * W2[(k + jj) * NCLS + c];
  }
  float m = acc[0];
#pragma unroll
  for (int c = 1; c < NCLS; c++) m = fmaxf(m, acc[c]);
  float s = 0.f;
#pragma unroll
  for (int c = 0; c < NCLS; c++) s += expf(acc[c] - m);
  float lse = logf(s) + m;
#pragma unroll
  for (int c = 0; c < NCLS; c++) op[(size_t)n * NCLS + c] = acc[c] - lse;
}

// =============================================================================
extern "C" void kernel_launch(void* const* d_in, const int* in_sizes, int n_in,
                              void* d_out, int out_size, void* d_ws, size_t ws_size,
                              hipStream_t stream) {
  const int N = in_sizes[0] / H;
  const int E = in_sizes[1] / 2;
  const float* x = (const float*)d_in[0];
  const int* ei = (const int*)d_in[1];
  const int* row = ei;
  const int* col = ei + E;
  const int* perm = (const int*)d_in[2];
  const float* W_feat = (const float*)d_in[3];
  const float* b_feat = (const float*)d_in[4];
  const float* W_convs = (const float*)d_in[5];
  const float* b_convs = (const float*)d_in[6];
  const float* W_ea = (const float*)d_in[7];
  const float* b_ea = (const float*)d_in[8];
  const float* W_na = (const float*)d_in[9];
  const float* b_na = (const float*)d_in[10];
  const float* W_ctx = (const float*)d_in[11];
  const float* b_ctx = (const float*)d_in[12];
  const float* W_obj = (const float*)d_in[13];
  const float* b_obj = (const float*)d_in[14];
  const float* W_fc1 = (const float*)d_in[15];
  const float* b_fc1 = (const float*)d_in[16];
  const float* W_fc2 = (const float*)d_in[17];
  const float* b_fc2 = (const float*)d_in[18];
  float* out = (float*)d_out;

  const int gG = (N + 63) / 64;
  const int gN = (N + 255) / 256;
  const int gE = (E + 255) / 256;
  const int SB = (N + 255) / 256;
  const int n4 = N * 32;
  const int gAgg = (N + 3) / 4;
  const float invN = 1.0f / (float)N;

  // ---------- workspace carve (~84 MB; <=86 MB proven safe) ----------
  char* base = (char*)d_ws;
  size_t off_b = 0;
  auto alloc = [&](size_t bytes) -> void* {
    void* p = base + off_b;
    off_b = (off_b + bytes + 255) & ~(size_t)255;
    return p;
  };
  size_t NB2 = (size_t)N * H * sizeof(u16);
  u16* bufA = (u16*)alloc(NB2);  // h chain; hco; z2
  u16* bufB = (u16*)alloc(NB2);  // conv g temp
  u16* bufC = (u16*)alloc(NB2);  // gc -> xc -> z0
  u16* bufD = (u16*)alloc(NB2);  // go -> xo -> z1
  int* cnt = (int*)alloc(3 * (size_t)N * 4);  // cnt, deg, degc (one memset)
  float* deg = (float*)(cnt + N);
  float* degc = (float*)(cnt + 2 * (size_t)N);
  float* stpX = (float*)alloc((size_t)CS_BLOCKS * 256 * 4);   // x stats
  float* stpG = (float*)alloc(3 * (size_t)gG * 256 * 4);      // gemm-epilogue stats
  float* stpPre = (float*)alloc((size_t)CS_BLOCKS * 512 * 4); // xc_pre/xo_pre stats
  float* stpCO = (float*)alloc((size_t)CS_BLOCKS * 256 * 4);  // hco stats
  int* off = (int*)alloc(((size_t)N + 1) * 4);
  int* cur = (int*)alloc((size_t)N * 4);
  float* dinv = (float*)alloc((size_t)N * 4);
  float* dinvc = (float*)alloc((size_t)N * 4);
  float* dinvo = (float*)alloc((size_t)N * 4);
  float* sumw_n = (float*)alloc((size_t)N * 4);
  float* sumw_c = (float*)alloc((size_t)N * 4);
  float* sumw_o = (float*)alloc((size_t)N * 4);
  float2* na01 = (float2*)alloc((size_t)N * 8);
  float2* p01 = (float2*)alloc((size_t)N * 8);
  float2* q01 = (float2*)alloc((size_t)N * 8);
  int* partial = (int*)alloc(256 * 4);
  int* blockoff = (int*)alloc(256 * 4);
  u16* Wt = (u16*)alloc((size_t)H * H * 2);
  u16* Wt2 = (u16*)alloc(2 * (size_t)H * H * 2);
  u16* Wt3 = (u16*)alloc(3 * (size_t)H * H * 2);
  float* cf = (float*)alloc(H * 4);
  float* cf2 = (float*)alloc(2 * H * 4);
  float* cf3 = (float*)alloc(3 * H * 4);
  float* W2f = (float*)alloc(3 * (size_t)H * NCLS * 4);
  float* c2f = (float*)alloc(3 * 16 * 4);
  int* csr_src = (int*)alloc((size_t)E * 4);
  int* slot_of = (int*)alloc((size_t)E * 4);
  float* att0s = (float*)alloc((size_t)E * 4);
  float* wn = (float*)alloc((size_t)E * 4);
  float2* wfa = (float2*)alloc((size_t)E * 8);
  float2* wfr = (float2*)alloc((size_t)E * 8);

  // ---------- contended accumulators zeroed once ----------
  hipMemsetAsync(cnt, 0, 3 * (size_t)N * 4, stream);

  // ---------- CSR + degrees ----------
  hist_kernel<<<gE, 256, 0, stream>>>(row, col, E, cnt, deg);
  scanA_rsqrt_kernel<<<SB, 256, 0, stream>>>(cnt, deg, N, partial, dinv);
  scanB_kernel<<<1, 256, 0, stream>>>(partial, SB, blockoff);
  scanC_kernel<<<SB, 256, 0, stream>>>(cnt, N, blockoff, off, cur, E);
  place_kernel<<<gE, 256, 0, stream>>>(row, col, E, cur, dinv, csr_src, slot_of, wn);

  // ---------- feature layer (reads fp32 x directly; stats epilogue) ----------
  xstats_kernel<<<CS_BLOCKS, 256, 0, stream>>>(x, n4, stpX);
  fold_kernel<<<H, H, 0, stream>>>(stpX, CS_BLOCKS, W_feat, b_feat, invN, Wt, cf);
  gemm_x_kernel<<<gG, 256, 0, stream>>>(x, Wt, cf, bufA, N, stpG);

  // ---------- 3 GCN convs via linearity: agg(h)->g, then gemm w/ sumw --------
  for (int i = 0; i < 3; ++i) {
    fold_kernel<<<H, H, 0, stream>>>(stpG, gG, W_convs + (size_t)i * H * H,
                                     nullptr, invN, Wt, cf);
    aggn_kernel<<<gAgg, 256, 0, stream>>>(bufA, csr_src, wn, off, dinv, bufB,
                                          (i == 0) ? sumw_n : nullptr, N);
    gemmsw_kernel<<<gG, 256, 0, stream>>>(bufB, Wt, cf, b_convs + (size_t)i * H,
                                          sumw_n, bufA, N, stpG);
  }

  // ---------- attention ----------
  natt_kernel<<<gN, 256, 0, stream>>>(bufA, N, W_na, b_na, W_ea, na01, p01, q01);
  eatt_kernel<<<gE, 256, 0, stream>>>(row, col, E, p01, q01, b_ea, slot_of, att0s, degc);
  rsqrt2_kernel<<<gN, 256, 0, stream>>>(deg, degc, dinvc, dinvo, N);
  wa2_kernel<<<gE, 256, 0, stream>>>(csr_src, att0s, dinvc, dinvo, na01, wfa, wfr, E);
  xprestats_kernel<<<CS_BLOCKS, 256, 0, stream>>>(bufA, na01, n4, stpPre);

  // ---------- ctx + obj convs: agg(h) -> gemm ----------
  fold2_kernel<<<2 * H, H, 0, stream>>>(stpPre, CS_BLOCKS, W_ctx, W_obj, invN, Wt2, cf2);
  aggdual_kernel<<<gAgg, 256, 0, stream>>>(bufA, csr_src, wfa, wfr, off, dinvc,
                                           dinvo, na01, bufC, bufD, sumw_c, sumw_o, N);
  gemm2sw_kernel<<<2 * gG, 256, 0, stream>>>(bufC, bufD, Wt2, cf2, b_ctx, b_obj,
                                             sumw_c, sumw_o, N, gG, stpG);
  // xc=bufC, xo=bufD; stats in stpG[0..2*gG)

  // ---------- h_co = xc[perm] + xo (+stats) ----------
  permadd_stats_kernel<<<CS_BLOCKS, 256, 0, stream>>>(bufC, bufD, perm, bufA, n4, stpCO);

  // ---------- 3 readouts, fully batched, in-place ----------
  fold3_kernel<<<3 * H, H, 0, stream>>>(stpG, gG, stpG + (size_t)gG * 256, gG,
                                        stpCO, CS_BLOCKS, W_fc1, b_fc1, invN, Wt3, cf3);
  gemm3_kernel<<<3 * gG, 256, 0, stream>>>(bufC, bufD, bufA, Wt3, cf3, N, gG, stpG);
  fold10x3_kernel<<<3 * NCLS, H, 0, stream>>>(stpG, gG, W_fc2, b_fc2, invN, W2f, c2f);
  fc2x3_kernel<<<3 * gN, 256, 0, stream>>>(bufC, bufD, bufA, W2f, c2f, out, N, gN);
}

// Round 12
// 904.508 us; speedup vs baseline: 1.0724x; 1.0724x over previous
//
#include <hip/hip_runtime.h>
#include <math.h>

#define H 128
#define NCLS 10
#define EPS 1e-5f
#define BN_BETA 1e-4f
#define CS_BLOCKS 256

typedef unsigned short u16;
typedef unsigned int u32;
typedef __attribute__((ext_vector_type(8))) short short8;
typedef __attribute__((ext_vector_type(4))) float floatx4;

// ---- bf16 helpers (bit ops; RNE) ----
__device__ inline float bflo(u32 u) { union { u32 i; float f; } a; a.i = u << 16; return a.f; }
__device__ inline float bfhi(u32 u) { union { u32 i; float f; } a; a.i = u & 0xffff0000u; return a.f; }
__device__ inline u16 f2bf(float f) {
  union { float f; u32 i; } v; v.f = f;
  return (u16)((v.i + 0x7fff + ((v.i >> 16) & 1)) >> 16);
}
__device__ inline u32 pack2(float a, float b) { return (u32)f2bf(a) | ((u32)f2bf(b) << 16); }

// ---- latency-tolerant partial-row reduction: 8 independent streams ----------
__device__ inline void reduce_partials(const float* __restrict__ P, int nb, int stride,
                                       int off0, int f, float* su_out, float* sq_out) {
  float su[8] = {0, 0, 0, 0, 0, 0, 0, 0}, sq[8] = {0, 0, 0, 0, 0, 0, 0, 0};
  int b = 0;
  for (; b + 8 <= nb; b += 8) {
#pragma unroll
    for (int u = 0; u < 8; u++) {
      const float* p = P + (size_t)(b + u) * stride + off0;
      su[u] += p[f];
      sq[u] += p[128 + f];
    }
  }
  for (; b < nb; b++) {
    const float* p = P + (size_t)b * stride + off0;
    su[0] += p[f];
    sq[0] += p[128 + f];
  }
  *su_out = ((su[0] + su[1]) + (su[2] + su[3])) + ((su[4] + su[5]) + (su[6] + su[7]));
  *sq_out = ((sq[0] + sq[1]) + (sq[2] + sq[3])) + ((sq[4] + sq[5]) + (sq[6] + sq[7]));
}

// ---- fold body for 256 threads: 2 output columns per block -----------------
__device__ inline void fold256_body(const float* P, int nb, int stride, int off0,
                                    const float* W, const float* bias, float invN,
                                    int kp, u16* Wt, float* cf) {
  int f = threadIdx.x & 127;
  int half = threadIdx.x >> 7;
  int k = kp * 2 + half;
  float su, sq;
  reduce_partials(P, nb, stride, off0, f, &su, &sq);
  float mu = su * invN;
  float var = sq * invN - mu * mu;
  float s = 1.0f / sqrtf(fmaxf(var, 0.f) + EPS);
  float w = W[(size_t)f * H + k];
  Wt[(size_t)k * H + f] = f2bf(s * w);
  __shared__ float red[2][128];
  red[half][f] = (BN_BETA - mu * s) * w;
  __syncthreads();
  for (int o = 64; o > 0; o >>= 1) {
    if (f < o) red[half][f] += red[half][f + o];
    __syncthreads();
  }
  if (f == 0) cf[k] = red[half][0] + (bias ? bias[k] : 0.f);
}

// ================= small device bodies ======================================
__device__ inline void hist_body(const int* __restrict__ row, const int* __restrict__ col,
                                 int E, int* cnt, float* deg, int blk) {
  int e = blk * 256 + threadIdx.x;
  if (e < E) {
    atomicAdd(&cnt[col[e]], 1);
    atomicAdd(&deg[row[e]], 1.0f);
  }
}

__device__ inline void xstats_body(const float* __restrict__ x, int n4,
                                   float* __restrict__ stp, int blk) {
  int tid = threadIdx.x;
  int lane = tid & 63, wave = tid >> 6;
  float s[4] = {0, 0, 0, 0}, q[4] = {0, 0, 0, 0};
  int step = CS_BLOCKS * 256;
  for (int i = blk * 256 + tid; i < n4; i += step) {
    float4 v = ((const float4*)x)[i];
    s[0] += v.x; q[0] += v.x * v.x; s[1] += v.y; q[1] += v.y * v.y;
    s[2] += v.z; q[2] += v.z * v.z; s[3] += v.w; q[3] += v.w * v.w;
  }
#pragma unroll
  for (int k = 0; k < 4; k++) { s[k] += __shfl_xor(s[k], 32); q[k] += __shfl_xor(q[k], 32); }
  __shared__ float smx[4][256];
  int col = (lane & 31) * 4;
  if (lane < 32) {
#pragma unroll
    for (int k = 0; k < 4; k++) { smx[wave][col + k] = s[k]; smx[wave][128 + col + k] = q[k]; }
  }
  __syncthreads();
  stp[(size_t)blk * 256 + tid] = smx[0][tid] + smx[1][tid] + smx[2][tid] + smx[3][tid];
}

__device__ inline void scanA_body(const int* cnt, const float* deg, int N,
                                  int* partial, float* dinv, float* degc, int blk) {
  int i = blk * 256 + threadIdx.x;
  if (i < N) {
    dinv[i] = 1.0f / sqrtf(deg[i] + 1.0f);
    degc[i] = 0.f;
  }
  __shared__ int sdA[256];
  sdA[threadIdx.x] = (i < N) ? cnt[i] : 0;
  __syncthreads();
  for (int o = 128; o > 0; o >>= 1) {
    if (threadIdx.x < o) sdA[threadIdx.x] += sdA[threadIdx.x + o];
    __syncthreads();
  }
  if (threadIdx.x == 0) partial[blk] = sdA[0];
}

__device__ inline void scanB_body(const int* partial, int nb, int* blockoff) {
  __shared__ int sdB[256];
  int t = threadIdx.x;
  int v = (t < nb) ? partial[t] : 0;
  sdB[t] = v;
  __syncthreads();
  for (int o = 1; o < 256; o <<= 1) {
    int x = (t >= o) ? sdB[t - o] : 0;
    __syncthreads();
    sdB[t] += x;
    __syncthreads();
  }
  blockoff[t] = sdB[t] - v;
}

__device__ inline void scanC_body(const int* cnt, int N, const int* blockoff,
                                  int* off, int* cur, int E, int blk) {
  __shared__ int sdC[256];
  int t = threadIdx.x;
  int i = blk * 256 + t;
  int v = (i < N) ? cnt[i] : 0;
  sdC[t] = v;
  __syncthreads();
  for (int o = 1; o < 256; o <<= 1) {
    int x = (t >= o) ? sdC[t - o] : 0;
    __syncthreads();
    sdC[t] += x;
    __syncthreads();
  }
  if (i < N) {
    int ex = blockoff[blk] + sdC[t] - v;
    off[i] = ex;
    cur[i] = ex;
  }
  if (i == 0) off[N] = E;
}

__device__ inline void place_body(const int* row, const int* col, int E, int* cur,
                                  const float* dinv, int* csr_src, int* slot_of,
                                  float* wn, int blk) {
  int e = blk * 256 + threadIdx.x;
  if (e < E) {
    int r = row[e];
    int slot = atomicAdd(&cur[col[e]], 1);
    csr_src[slot] = r;
    slot_of[e] = slot;
    wn[slot] = dinv[r];
  }
}

__device__ inline void eatt_body(const int* row, const int* col, int E,
                                 const float2* p01, const float2* q01,
                                 const float* b_ea, const int* slot_of,
                                 float* att0s, float* degc, int blk) {
  int e = blk * 256 + threadIdx.x;
  if (e >= E) return;
  int r = row[e], c = col[e];
  float2 p = p01[r], q = q01[c];
  float l0 = p.x + q.x + b_ea[0];
  float l1 = p.y + q.y + b_ea[1];
  float a0 = 1.0f / (1.0f + expf(l1 - l0));
  att0s[slot_of[e]] = a0;
  atomicAdd(&degc[r], a0);
}

__device__ inline void xprestats_body(const u16* __restrict__ h,
                                      const float2* __restrict__ na01, int n4,
                                      float* __restrict__ stp, int blk) {
  int tid = threadIdx.x;
  int lane = tid & 63, wave = tid >> 6;
  float sc[4] = {0, 0, 0, 0}, qc[4] = {0, 0, 0, 0};
  float so[4] = {0, 0, 0, 0}, qo[4] = {0, 0, 0, 0};
  int step = CS_BLOCKS * 256;
  for (int i = blk * 256 + tid; i < n4; i += step) {
    int n = i >> 5;
    uint2 u = ((const uint2*)h)[i];
    float v0 = bflo(u.x), v1 = bfhi(u.x), v2 = bflo(u.y), v3 = bfhi(u.y);
    float2 ab = na01[n];
    float a = ab.x, b = ab.y;
    float c0 = v0 * a, c1 = v1 * a, c2 = v2 * a, c3 = v3 * a;
    float o0 = v0 * b, o1 = v1 * b, o2 = v2 * b, o3 = v3 * b;
    sc[0] += c0; qc[0] += c0 * c0; sc[1] += c1; qc[1] += c1 * c1;
    sc[2] += c2; qc[2] += c2 * c2; sc[3] += c3; qc[3] += c3 * c3;
    so[0] += o0; qo[0] += o0 * o0; so[1] += o1; qo[1] += o1 * o1;
    so[2] += o2; qo[2] += o2 * o2; so[3] += o3; qo[3] += o3 * o3;
  }
#pragma unroll
  for (int k = 0; k < 4; k++) {
    sc[k] += __shfl_xor(sc[k], 32); qc[k] += __shfl_xor(qc[k], 32);
    so[k] += __shfl_xor(so[k], 32); qo[k] += __shfl_xor(qo[k], 32);
  }
  __shared__ float smp[4][512];
  int col = (lane & 31) * 4;
  if (lane < 32) {
#pragma unroll
    for (int k = 0; k < 4; k++) {
      smp[wave][col + k] = sc[k];
      smp[wave][128 + col + k] = qc[k];
      smp[wave][256 + col + k] = so[k];
      smp[wave][384 + col + k] = qo[k];
    }
  }
  __syncthreads();
  float r0 = smp[0][tid] + smp[1][tid] + smp[2][tid] + smp[3][tid];
  float r1 = smp[0][256 + tid] + smp[1][256 + tid] + smp[2][256 + tid] + smp[3][256 + tid];
  stp[(size_t)blk * 512 + tid] = r0;
  stp[(size_t)blk * 512 + 256 + tid] = r1;
}

// wa2: per-slot packed weights, dinvc/dinvo computed inline from deg/degc
__device__ inline void wa2_body(const int* csr_src, const float* att0s,
                                const float* deg, const float* degc,
                                const float2* na01, float2* wfa, float2* wfr,
                                int E, int blk) {
  int i = blk * 256 + threadIdx.x;
  if (i >= E) return;
  int s = csr_src[i];
  float a0 = att0s[i];
  float2 na = na01[s];
  float dgc = degc[s];
  float r0 = a0 / sqrtf(dgc + 1.0f);
  float r1 = (1.0f - a0) / sqrtf(deg[s] - dgc + 1.0f);
  wfa[i] = make_float2(r0 * na.x, r1 * na.y);
  wfr[i] = make_float2(r0, r1);
}

// ================= bf16 MFMA GEMM core ======================================
__device__ inline void gemm_core(const u16* A, const float* Afp, const u16* Bt,
                                 const float* cf, const float* b2, const float* sumw,
                                 u16* C, int N, int relu, int blk, float* stp) {
  int tid = threadIdx.x;
  int wave = tid >> 6, lane = tid & 63;
  int l15 = lane & 15, quad = lane >> 4;
  int row0 = (blk * 4 + wave) * 16;
  if (row0 >= N && !stp) return;
  int arow = row0 + l15;
  short8 a[4];
  short8 z8 = {0, 0, 0, 0, 0, 0, 0, 0};
  if (Afp) {
#pragma unroll
    for (int k4 = 0; k4 < 4; k4++) {
      if (arow < N) {
        const float* p = Afp + (size_t)arow * H + k4 * 32 + quad * 8;
        float4 f0 = *(const float4*)p;
        float4 f1 = *(const float4*)(p + 4);
        union { short8 s8; u32 u[4]; } cv;
        cv.u[0] = pack2(f0.x, f0.y); cv.u[1] = pack2(f0.z, f0.w);
        cv.u[2] = pack2(f1.x, f1.y); cv.u[3] = pack2(f1.z, f1.w);
        a[k4] = cv.s8;
      } else a[k4] = z8;
    }
  } else {
#pragma unroll
    for (int k4 = 0; k4 < 4; k4++)
      a[k4] = (arow < N) ? *(const short8*)(A + (size_t)arow * H + k4 * 32 + quad * 8) : z8;
  }
  float srow[4];
  if (sumw) {
#pragma unroll
    for (int r = 0; r < 4; r++) {
      int row = row0 + quad * 4 + r;
      srow[r] = (row < N) ? sumw[row] : 0.f;
    }
  }
  float ps[8], pq[8];
#pragma unroll
  for (int nt = 0; nt < 8; nt++) {
    floatx4 acc = {0.f, 0.f, 0.f, 0.f};
    const u16* bp = Bt + (size_t)(nt * 16 + l15) * H + quad * 8;
#pragma unroll
    for (int k4 = 0; k4 < 4; k4++) {
      short8 b = *(const short8*)(bp + k4 * 32);
      acc = __builtin_amdgcn_mfma_f32_16x16x32_bf16(a[k4], b, acc, 0, 0, 0);
    }
    int col = nt * 16 + l15;
    float base = cf[col];
    float bb = b2 ? b2[col] : 0.f;
    float s_ = 0.f, q_ = 0.f;
#pragma unroll
    for (int r = 0; r < 4; r++) {
      int row = row0 + quad * 4 + r;
      if (row < N) {
        float v = acc[r] + (sumw ? srow[r] * base + bb : base);
        if (relu) v = fmaxf(v, 0.f);
        s_ += v; q_ += v * v;
        C[(size_t)row * H + col] = f2bf(v);
      }
    }
    ps[nt] = s_; pq[nt] = q_;
  }
  if (stp) {
    __shared__ float sred[4][256];
#pragma unroll
    for (int nt = 0; nt < 8; nt++) {
      ps[nt] += __shfl_xor(ps[nt], 16); ps[nt] += __shfl_xor(ps[nt], 32);
      pq[nt] += __shfl_xor(pq[nt], 16); pq[nt] += __shfl_xor(pq[nt], 32);
    }
    if (quad == 0) {
#pragma unroll
      for (int nt = 0; nt < 8; nt++) {
        sred[wave][nt * 16 + l15] = ps[nt];
        sred[wave][128 + nt * 16 + l15] = pq[nt];
      }
    }
    __syncthreads();
    stp[(size_t)blk * 256 + tid] =
        sred[0][tid] + sred[1][tid] + sred[2][tid] + sred[3][tid];
  }
}

// ================= merged kernels ===========================================
__global__ __launch_bounds__(256) void hist_xstats_kernel(
    const int* row, const int* col, int E, int* cnt, float* deg, int gE,
    const float* x, int n4, float* stpX) {
  if ((int)blockIdx.x < gE) hist_body(row, col, E, cnt, deg, blockIdx.x);
  else xstats_body(x, n4, stpX, blockIdx.x - gE);
}

__global__ __launch_bounds__(256) void scanA_fold_kernel(
    const int* cnt, const float* deg, int N, int* partial, float* dinv, float* degc,
    int SB, const float* stpX, const float* W_feat, const float* b_feat, float invN,
    u16* WtA, float* cfA) {
  if ((int)blockIdx.x < SB) scanA_body(cnt, deg, N, partial, dinv, degc, blockIdx.x);
  else fold256_body(stpX, CS_BLOCKS, 256, 0, W_feat, b_feat, invN, blockIdx.x - SB, WtA, cfA);
}

__global__ __launch_bounds__(256) void scanB_gemmx_kernel(
    const int* partial, int nb, int* blockoff,
    const float* x, const u16* WtA, const float* cfA, u16* C, int N, float* stpG) {
  if (blockIdx.x == 0) scanB_body(partial, nb, blockoff);
  else gemm_core(nullptr, x, WtA, cfA, nullptr, nullptr, C, N, 1, blockIdx.x - 1, stpG);
}

__global__ __launch_bounds__(256) void scanC_fold_kernel(
    const int* cnt, int N, const int* blockoff, int* off, int* cur, int E, int SB,
    const float* stpG, int nbG, const float* Wc, float invN, u16* WtB, float* cfB) {
  if ((int)blockIdx.x < SB) scanC_body(cnt, N, blockoff, off, cur, E, blockIdx.x);
  else fold256_body(stpG, nbG, 256, 0, Wc, nullptr, invN, blockIdx.x - SB, WtB, cfB);
}

__global__ __launch_bounds__(256) void place_gemm_kernel(
    const int* row, const int* col, int E, int* cur, const float* dinv,
    int* csr_src, int* slot_of, float* wn, int gE,
    const u16* A, const u16* WtB, const float* cfB, u16* C, int N) {
  if ((int)blockIdx.x < gE)
    place_body(row, col, E, cur, dinv, csr_src, slot_of, wn, blockIdx.x);
  else
    gemm_core(A, nullptr, WtB, cfB, nullptr, nullptr, C, N, 0, blockIdx.x - gE, nullptr);
}

__global__ __launch_bounds__(256) void eatt_xpre_kernel(
    const int* row, const int* col, int E, const float2* p01, const float2* q01,
    const float* b_ea, const int* slot_of, float* att0s, float* degc, int gE,
    const u16* h, const float2* na01, int n4, float* stpPre) {
  if ((int)blockIdx.x < gE)
    eatt_body(row, col, E, p01, q01, b_ea, slot_of, att0s, degc, blockIdx.x);
  else
    xprestats_body(h, na01, n4, stpPre, blockIdx.x - gE);
}

__global__ __launch_bounds__(256) void wa2_fold2_kernel(
    const int* csr_src, const float* att0s, const float* deg, const float* degc,
    const float2* na01, float2* wfa, float2* wfr, int E, int gE,
    const float* stpPre, const float* W_ctx, const float* W_obj, float invN,
    u16* Wt2, float* cf2) {
  if ((int)blockIdx.x < gE)
    wa2_body(csr_src, att0s, deg, degc, na01, wfa, wfr, E, blockIdx.x);
  else {
    int b = blockIdx.x - gE;  // 0..127
    int j = b >> 6, kp = b & 63;
    fold256_body(stpPre, CS_BLOCKS, 512, j * 256, j ? W_obj : W_ctx, nullptr, invN, kp,
                 Wt2 + (size_t)j * H * H, cf2 + j * H);
  }
}

// ================= standalone kernels =======================================
__global__ __launch_bounds__(256) void fold256_kernel(
    const float* P, int nb, const float* W, const float* bias, float invN,
    u16* Wt, float* cf) {
  fold256_body(P, nb, 256, 0, W, bias, invN, blockIdx.x, Wt, cf);
}

__global__ __launch_bounds__(256) void fold3_kernel(
    const float* PC, int nbC, const float* PO, int nbO, const float* PCO, int nbCO,
    const float* W_fc1, const float* b_fc1, float invN, u16* Wt3, float* cf3) {
  int j = blockIdx.x / 64, kp = blockIdx.x % 64;
  const float* P = (j == 0) ? PC : (j == 1) ? PO : PCO;
  int nb = (j == 0) ? nbC : (j == 1) ? nbO : nbCO;
  fold256_body(P, nb, 256, 0, W_fc1 + (size_t)j * H * H, b_fc1 + j * H, invN, kp,
               Wt3 + (size_t)j * H * H, cf3 + j * H);
}

__global__ __launch_bounds__(128) void fold10x3_kernel(
    const float* stpZ, int nb, const float* W_fc2, const float* b_fc2, float invN,
    float* W2f, float* c2f) {
  int j = blockIdx.x / NCLS, k = blockIdx.x % NCLS;
  const float* P = stpZ + (size_t)j * nb * 256;
  int f = threadIdx.x;
  float su, sq;
  reduce_partials(P, nb, 256, 0, f, &su, &sq);
  float mu = su * invN;
  float var = sq * invN - mu * mu;
  float s = 1.0f / sqrtf(fmaxf(var, 0.f) + EPS);
  float w = W_fc2[(size_t)j * H * NCLS + (size_t)f * NCLS + k];
  W2f[(size_t)j * H * NCLS + (size_t)f * NCLS + k] = s * w;
  __shared__ float red1[H];
  red1[f] = (BN_BETA - mu * s) * w;
  __syncthreads();
  for (int o = 64; o > 0; o >>= 1) {
    if (f < o) red1[f] += red1[f + o];
    __syncthreads();
  }
  if (f == 0) c2f[j * 16 + k] = red1[0] + b_fc2[j * NCLS + k];
}

__global__ __launch_bounds__(256) void gemm_kernel(
    const u16* A, const u16* Bt, const float* cf, u16* C, int N, int relu) {
  gemm_core(A, nullptr, Bt, cf, nullptr, nullptr, C, N, relu, blockIdx.x, nullptr);
}

__global__ __launch_bounds__(256) void gemm2sw_kernel(
    u16* B0, u16* B1, const u16* Wt2, const float* cf2,
    const float* b0, const float* b1, const float* sw0, const float* sw1,
    int N, int gG, float* stp) {
  int j = blockIdx.x / gG, blk = blockIdx.x % gG;
  u16* Z = j ? B1 : B0;
  gemm_core(Z, nullptr, Wt2 + (size_t)j * H * H, cf2 + j * H, j ? b1 : b0,
            j ? sw1 : sw0, Z, N, 1, blk, stp + (size_t)j * gG * 256);
}

__global__ __launch_bounds__(256) void gemm3_kernel(
    u16* Z0, u16* Z1, u16* Z2, const u16* Wt3, const float* cf3,
    int N, int gG, float* stp) {
  int j = blockIdx.x / gG, blk = blockIdx.x % gG;
  u16* Z = (j == 0) ? Z0 : (j == 1) ? Z1 : Z2;
  gemm_core(Z, nullptr, Wt3 + (size_t)j * H * H, cf3 + j * H, nullptr, nullptr,
            Z, N, 1, blk, stp + (size_t)j * gG * 256);
}

// ================= column stats over bf16 [N,128] (no atomics) ===============
__global__ __launch_bounds__(256) void colstats_kernel(
    const u16* __restrict__ X, int N, float* __restrict__ stp) {
  int tid = threadIdx.x;
  int li = tid & 15, rg = tid >> 4;
  int wave = tid >> 6, lane = tid & 63;
  const uint4* T = (const uint4*)X;
  float s[8] = {0, 0, 0, 0, 0, 0, 0, 0}, q[8] = {0, 0, 0, 0, 0, 0, 0, 0};
  for (int r = blockIdx.x * 16 + rg; r < N; r += CS_BLOCKS * 16) {
    uint4 u = T[(size_t)r * 16 + li];
    float f[8] = {bflo(u.x), bfhi(u.x), bflo(u.y), bfhi(u.y),
                  bflo(u.z), bfhi(u.z), bflo(u.w), bfhi(u.w)};
#pragma unroll
    for (int j = 0; j < 8; j++) { s[j] += f[j]; q[j] += f[j] * f[j]; }
  }
#pragma unroll
  for (int j = 0; j < 8; j++) {
    s[j] += __shfl_xor(s[j], 16); s[j] += __shfl_xor(s[j], 32);
    q[j] += __shfl_xor(q[j], 16); q[j] += __shfl_xor(q[j], 32);
  }
  __shared__ float smc[4][256];
  if ((lane & 48) == 0) {
#pragma unroll
    for (int j = 0; j < 8; j++) {
      smc[wave][li * 8 + j] = s[j];
      smc[wave][128 + li * 8 + j] = q[j];
    }
  }
  __syncthreads();
  stp[(size_t)blockIdx.x * 256 + tid] = smc[0][tid] + smc[1][tid] + smc[2][tid] + smc[3][tid];
}

// ================= aggregation (r10 structure: bias+relu inside) =============
#define ACC8(A, U, W)                                             \
  A[0] += (W) * bflo(U.x); A[1] += (W) * bfhi(U.x);               \
  A[2] += (W) * bflo(U.y); A[3] += (W) * bfhi(U.y);               \
  A[4] += (W) * bflo(U.z); A[5] += (W) * bfhi(U.z);               \
  A[6] += (W) * bflo(U.w); A[7] += (W) * bfhi(U.w);

__global__ __launch_bounds__(256) void agg_kernel(
    const u16* __restrict__ t, const int* __restrict__ csr_src,
    const float* __restrict__ wseg, const int* __restrict__ off,
    const float* __restrict__ dinv, const float* __restrict__ bias,
    u16* __restrict__ out, int N) {
  int v = blockIdx.x * 4 + (threadIdx.x >> 6);
  if (v >= N) return;
  int lane = threadIdx.x & 63;
  int g = lane >> 4, li = lane & 15;
  const uint4* T = (const uint4*)t;
  float dv = dinv[v];
  float acc[8] = {0.f, 0.f, 0.f, 0.f, 0.f, 0.f, 0.f, 0.f};
  if (g == 0) {
    uint4 u = T[(size_t)v * 16 + li];
    float w0 = dv * dv;
    ACC8(acc, u, w0)
  }
  int s0 = off[v], s1 = off[v + 1];
  for (int s = s0; s < s1; s += 32) {
    int ix[8]; float wv[8];
#pragma unroll
    for (int u = 0; u < 8; u++) {
      int e = s + g + u * 4;
      bool ok = e < s1;
      int e2 = ok ? e : s0;
      ix[u] = csr_src[e2];
      wv[u] = ok ? wseg[e2] : 0.f;
    }
    uint4 uu[8];
#pragma unroll
    for (int u = 0; u < 8; u++) uu[u] = T[(size_t)ix[u] * 16 + li];
#pragma unroll
    for (int u = 0; u < 8; u++) { float w = wv[u] * dv; ACC8(acc, uu[u], w) }
  }
#pragma unroll
  for (int j = 0; j < 8; j++) {
    acc[j] += __shfl_xor(acc[j], 16);
    acc[j] += __shfl_xor(acc[j], 32);
  }
  if (g == 0) {
    float o[8];
#pragma unroll
    for (int j = 0; j < 8; j++) o[j] = fmaxf(acc[j] + bias[li * 8 + j], 0.f);
    uint4 w4;
    w4.x = pack2(o[0], o[1]); w4.y = pack2(o[2], o[3]);
    w4.z = pack2(o[4], o[5]); w4.w = pack2(o[6], o[7]);
    ((uint4*)out)[(size_t)v * 16 + li] = w4;
  }
}

// ---- dual aggregation over shared table h (ctx + obj), inline deg norms ----
__global__ __launch_bounds__(256) void aggdual_kernel(
    const u16* __restrict__ h, const int* __restrict__ csr_src,
    const float2* __restrict__ wfa, const float2* __restrict__ wfr,
    const int* __restrict__ off, const float* __restrict__ deg,
    const float* __restrict__ degc, const float2* __restrict__ na01,
    u16* __restrict__ gc, u16* __restrict__ go,
    float* __restrict__ sumw_c, float* __restrict__ sumw_o, int N) {
  int v = blockIdx.x * 4 + (threadIdx.x >> 6);
  if (v >= N) return;
  int lane = threadIdx.x & 63;
  int g = lane >> 4, li = lane & 15;
  const uint4* T = (const uint4*)h;
  float dgc = degc[v];
  float dvc = 1.0f / sqrtf(dgc + 1.0f);
  float dvo = 1.0f / sqrtf(deg[v] - dgc + 1.0f);
  float ac[8] = {0.f, 0.f, 0.f, 0.f, 0.f, 0.f, 0.f, 0.f};
  float ao[8] = {0.f, 0.f, 0.f, 0.f, 0.f, 0.f, 0.f, 0.f};
  float swc = 0.f, swo = 0.f;
  if (g == 0) {
    uint4 u = T[(size_t)v * 16 + li];
    float2 na = na01[v];
    float wc = dvc * dvc, wo = dvo * dvo;
    float wch = wc * na.x, woh = wo * na.y;
    ACC8(ac, u, wch)
    ACC8(ao, u, woh)
  }
  int s0 = off[v], s1 = off[v + 1];
  for (int s = s0; s < s1; s += 16) {
    int ix[4]; float2 fa[4], fr[4];
#pragma unroll
    for (int u = 0; u < 4; u++) {
      int e = s + g + u * 4;
      bool ok = e < s1;
      int e2 = ok ? e : s0;
      ix[u] = csr_src[e2];
      fa[u] = ok ? wfa[e2] : make_float2(0.f, 0.f);
      fr[u] = ok ? wfr[e2] : make_float2(0.f, 0.f);
    }
    uint4 uu[4];
#pragma unroll
    for (int u = 0; u < 4; u++) uu[u] = T[(size_t)ix[u] * 16 + li];
#pragma unroll
    for (int u = 0; u < 4; u++) {
      float wc = fa[u].x * dvc; ACC8(ac, uu[u], wc)
      float wo = fa[u].y * dvo; ACC8(ao, uu[u], wo)
      swc += fr[u].x; swo += fr[u].y;
    }
  }
#pragma unroll
  for (int j = 0; j < 8; j++) {
    ac[j] += __shfl_xor(ac[j], 16); ac[j] += __shfl_xor(ac[j], 32);
    ao[j] += __shfl_xor(ao[j], 16); ao[j] += __shfl_xor(ao[j], 32);
  }
  swc += __shfl_xor(swc, 16); swc += __shfl_xor(swc, 32);
  swo += __shfl_xor(swo, 16); swo += __shfl_xor(swo, 32);
  if (g == 0) {
    uint4 wc4, wo4;
    wc4.x = pack2(ac[0], ac[1]); wc4.y = pack2(ac[2], ac[3]);
    wc4.z = pack2(ac[4], ac[5]); wc4.w = pack2(ac[6], ac[7]);
    wo4.x = pack2(ao[0], ao[1]); wo4.y = pack2(ao[2], ao[3]);
    wo4.z = pack2(ao[4], ao[5]); wo4.w = pack2(ao[6], ao[7]);
    ((uint4*)gc)[(size_t)v * 16 + li] = wc4;
    ((uint4*)go)[(size_t)v * 16 + li] = wo4;
    if (li == 0) {
      sumw_c[v] = dvc * swc + dvc * dvc;
      sumw_o[v] = dvo * swo + dvo * dvo;
    }
  }
}

// ================= node attention + edge-att p,q factors =====================
__global__ __launch_bounds__(256) void natt_kernel(
    const u16* __restrict__ h, int N,
    const float* __restrict__ W_na, const float* __restrict__ b_na,
    const float* __restrict__ W_ea,
    float2* __restrict__ na01, float2* __restrict__ p01, float2* __restrict__ q01) {
  int n = blockIdx.x * 256 + threadIdx.x;
  if (n >= N) return;
  float sa0 = 0, sa1 = 0, sp0 = 0, sp1 = 0, sq0 = 0, sq1 = 0;
  const uint2* hr = (const uint2*)(h + (size_t)n * H);
  for (int c = 0; c < 32; c++) {
    uint2 u = hr[c];
    float v0 = bflo(u.x), v1 = bfhi(u.x), v2 = bflo(u.y), v3 = bfhi(u.y);
    int k = c * 4;
    sa0 += v0 * W_na[k * 2] + v1 * W_na[k * 2 + 2] + v2 * W_na[k * 2 + 4] + v3 * W_na[k * 2 + 6];
    sa1 += v0 * W_na[k * 2 + 1] + v1 * W_na[k * 2 + 3] + v2 * W_na[k * 2 + 5] + v3 * W_na[k * 2 + 7];
    sp0 += v0 * W_ea[k * 2] + v1 * W_ea[k * 2 + 2] + v2 * W_ea[k * 2 + 4] + v3 * W_ea[k * 2 + 6];
    sp1 += v0 * W_ea[k * 2 + 1] + v1 * W_ea[k * 2 + 3] + v2 * W_ea[k * 2 + 5] + v3 * W_ea[k * 2 + 7];
    sq0 += v0 * W_ea[(H + k) * 2] + v1 * W_ea[(H + k) * 2 + 2] + v2 * W_ea[(H + k) * 2 + 4] + v3 * W_ea[(H + k) * 2 + 6];
    sq1 += v0 * W_ea[(H + k) * 2 + 1] + v1 * W_ea[(H + k) * 2 + 3] + v2 * W_ea[(H + k) * 2 + 5] + v3 * W_ea[(H + k) * 2 + 7];
  }
  sa0 += b_na[0]; sa1 += b_na[1];
  float m = fmaxf(sa0, sa1);
  float e0 = expf(sa0 - m), e1 = expf(sa1 - m);
  float inv = 1.f / (e0 + e1);
  na01[n] = make_float2(e0 * inv, e1 * inv);
  p01[n] = make_float2(sp0, sp1);
  q01[n] = make_float2(sq0, sq1);
}

// ================= h_co = xc[perm] + xo, fused stats =========================
__global__ __launch_bounds__(256) void permadd_stats_kernel(
    const u16* __restrict__ xc, const u16* __restrict__ xo,
    const int* __restrict__ perm, u16* __restrict__ out, int n4, float* __restrict__ stp) {
  int tid = threadIdx.x;
  int lane = tid & 63, wave = tid >> 6;
  float s[4] = {0, 0, 0, 0}, q[4] = {0, 0, 0, 0};
  int step = CS_BLOCKS * 256;
  for (int i = blockIdx.x * 256 + tid; i < n4; i += step) {
    int n = i >> 5, k = i & 31;
    int p = perm[n];
    uint2 a = ((const uint2*)xc)[(size_t)p * 32 + k];
    uint2 b = ((const uint2*)xo)[i];
    float f0 = bflo(a.x) + bflo(b.x), f1 = bfhi(a.x) + bfhi(b.x);
    float f2 = bflo(a.y) + bflo(b.y), f3 = bfhi(a.y) + bfhi(b.y);
    ((uint2*)out)[i] = make_uint2(pack2(f0, f1), pack2(f2, f3));
    s[0] += f0; q[0] += f0 * f0; s[1] += f1; q[1] += f1 * f1;
    s[2] += f2; q[2] += f2 * f2; s[3] += f3; q[3] += f3 * f3;
  }
#pragma unroll
  for (int k = 0; k < 4; k++) { s[k] += __shfl_xor(s[k], 32); q[k] += __shfl_xor(q[k], 32); }
  __shared__ float smq[4][256];
  int col = (lane & 31) * 4;
  if (lane < 32) {
#pragma unroll
    for (int k = 0; k < 4; k++) { smq[wave][col + k] = s[k]; smq[wave][128 + col + k] = q[k]; }
  }
  __syncthreads();
  stp[(size_t)blockIdx.x * 256 + tid] = smq[0][tid] + smq[1][tid] + smq[2][tid] + smq[3][tid];
}

// ================= fc2 x3: [N,128]@[128,10] + log_softmax ====================
__global__ __launch_bounds__(256) void fc2x3_kernel(
    const u16* __restrict__ z0, const u16* __restrict__ z1, const u16* __restrict__ z2,
    const float* __restrict__ W2f, const float* __restrict__ c2f,
    float* __restrict__ outp, int N, int gN) {
  int j = blockIdx.x / gN, blk = blockIdx.x % gN;
  int n = blk * 256 + threadIdx.x;
  if (n >= N) return;
  const u16* z = (j == 0) ? z0 : (j == 1) ? z1 : z2;
  const float* W2 = W2f + (size_t)j * H * NCLS;
  const float* c2 = c2f + j * 16;
  float* op = outp + (size_t)j * N * NCLS;
  float acc[NCLS];
#pragma unroll
  for (int c = 0; c < NCLS; c++) acc[c] = c2[c];
  const uint2* zr = (const uint2*)(z + (size_t)n * H);
  for (int c4 = 0; c4 < 32; c4++) {
    uint2 u = zr[c4];
    float v[4] = {bflo(u.x), bfhi(u.x), bflo(u.y), bfhi(u.y)};
    int k = c4 * 4;
#pragma unroll
    for (int jj = 0; jj < 4; jj++)
#pragma unroll
      for (int c = 0; c < NCLS; c++) acc[c] += v[jj] * W2[(k + jj) * NCLS + c];
  }
  float m = acc[0];
#pragma unroll
  for (int c = 1; c < NCLS; c++) m = fmaxf(m, acc[c]);
  float s = 0.f;
#pragma unroll
  for (int c = 0; c < NCLS; c++) s += expf(acc[c] - m);
  float lse = logf(s) + m;
#pragma unroll
  for (int c = 0; c < NCLS; c++) op[(size_t)n * NCLS + c] = acc[c] - lse;
}

// =============================================================================
extern "C" void kernel_launch(void* const* d_in, const int* in_sizes, int n_in,
                              void* d_out, int out_size, void* d_ws, size_t ws_size,
                              hipStream_t stream) {
  const int N = in_sizes[0] / H;
  const int E = in_sizes[1] / 2;
  const float* x = (const float*)d_in[0];
  const int* ei = (const int*)d_in[1];
  const int* row = ei;
  const int* col = ei + E;
  const int* perm = (const int*)d_in[2];
  const float* W_feat = (const float*)d_in[3];
  const float* b_feat = (const float*)d_in[4];
  const float* W_convs = (const float*)d_in[5];
  const float* b_convs = (const float*)d_in[6];
  const float* W_ea = (const float*)d_in[7];
  const float* b_ea = (const float*)d_in[8];
  const float* W_na = (const float*)d_in[9];
  const float* b_na = (const float*)d_in[10];
  const float* W_ctx = (const float*)d_in[11];
  const float* b_ctx = (const float*)d_in[12];
  const float* W_obj = (const float*)d_in[13];
  const float* b_obj = (const float*)d_in[14];
  const float* W_fc1 = (const float*)d_in[15];
  const float* b_fc1 = (const float*)d_in[16];
  const float* W_fc2 = (const float*)d_in[17];
  const float* b_fc2 = (const float*)d_in[18];
  float* out = (float*)d_out;

  const int gG = (N + 63) / 64;
  const int gN = (N + 255) / 256;
  const int gE = (E + 255) / 256;
  const int SB = (N + 255) / 256;
  const int n4 = N * 32;
  const int gAgg = (N + 3) / 4;
  const float invN = 1.0f / (float)N;

  // ---------- workspace carve (~84 MB) ----------
  char* base = (char*)d_ws;
  size_t off_b = 0;
  auto alloc = [&](size_t bytes) -> void* {
    void* p = base + off_b;
    off_b = (off_b + bytes + 255) & ~(size_t)255;
    return p;
  };
  size_t NB2 = (size_t)N * H * sizeof(u16);
  u16* bufA = (u16*)alloc(NB2);  // h chain; hco; z2
  u16* bufB = (u16*)alloc(NB2);  // conv t temp
  u16* bufC = (u16*)alloc(NB2);  // gc -> xc -> z0
  u16* bufD = (u16*)alloc(NB2);  // go -> xo -> z1
  int* cnt = (int*)alloc(2 * (size_t)N * 4);  // cnt, deg (one memset)
  float* deg = (float*)(cnt + N);
  float* degc = (float*)alloc((size_t)N * 4);  // zeroed in scanA
  float* stpX = (float*)alloc((size_t)CS_BLOCKS * 256 * 4);
  float* stpG = (float*)alloc(3 * (size_t)gG * 256 * 4);
  float* stpPre = (float*)alloc((size_t)CS_BLOCKS * 512 * 4);
  float* stpCO = (float*)alloc((size_t)CS_BLOCKS * 256 * 4);
  int* off = (int*)alloc(((size_t)N + 1) * 4);
  int* cur = (int*)alloc((size_t)N * 4);
  float* dinv = (float*)alloc((size_t)N * 4);
  float* sumw_c = (float*)alloc((size_t)N * 4);
  float* sumw_o = (float*)alloc((size_t)N * 4);
  float2* na01 = (float2*)alloc((size_t)N * 8);
  float2* p01 = (float2*)alloc((size_t)N * 8);
  float2* q01 = (float2*)alloc((size_t)N * 8);
  int* partial = (int*)alloc(256 * 4);
  int* blockoff = (int*)alloc(256 * 4);
  u16* WtA = (u16*)alloc((size_t)H * H * 2);
  u16* WtB = (u16*)alloc((size_t)H * H * 2);
  u16* Wt2 = (u16*)alloc(2 * (size_t)H * H * 2);
  u16* Wt3 = (u16*)alloc(3 * (size_t)H * H * 2);
  float* cfA = (float*)alloc(H * 4);
  float* cfB = (float*)alloc(H * 4);
  float* cf2 = (float*)alloc(2 * H * 4);
  float* cf3 = (float*)alloc(3 * H * 4);
  float* W2f = (float*)alloc(3 * (size_t)H * NCLS * 4);
  float* c2f = (float*)alloc(3 * 16 * 4);
  int* csr_src = (int*)alloc((size_t)E * 4);
  int* slot_of = (int*)alloc((size_t)E * 4);
  float* att0s = (float*)alloc((size_t)E * 4);
  float* wn = (float*)alloc((size_t)E * 4);
  float2* wfa = (float2*)alloc((size_t)E * 8);
  float2* wfr = (float2*)alloc((size_t)E * 8);

  // 1. zero cnt+deg
  hipMemsetAsync(cnt, 0, 2 * (size_t)N * 4, stream);

  // 2. hist || xstats
  hist_xstats_kernel<<<gE + CS_BLOCKS, 256, 0, stream>>>(row, col, E, cnt, deg, gE,
                                                         x, n4, stpX);
  // 3. scanA(+dinv,+degc=0) || fold(feat)
  scanA_fold_kernel<<<SB + 64, 256, 0, stream>>>(cnt, deg, N, partial, dinv, degc, SB,
                                                 stpX, W_feat, b_feat, invN, WtA, cfA);
  // 4. scanB || gemm_x (h0 -> bufA, stats -> stpG)
  scanB_gemmx_kernel<<<1 + gG, 256, 0, stream>>>(partial, SB, blockoff, x, WtA, cfA,
                                                 bufA, N, stpG);
  // 5. scanC || fold(conv0)
  scanC_fold_kernel<<<SB + 64, 256, 0, stream>>>(cnt, N, blockoff, off, cur, E, SB,
                                                 stpG, gG, W_convs, invN, WtB, cfB);
  // 6. place || gemm(conv0: bufA -> bufB)
  place_gemm_kernel<<<gE + gG, 256, 0, stream>>>(row, col, E, cur, dinv, csr_src,
                                                 slot_of, wn, gE, bufA, WtB, cfB,
                                                 bufB, N);
  // 7. agg(conv0) -> h1 in bufA
  agg_kernel<<<gAgg, 256, 0, stream>>>(bufB, csr_src, wn, off, dinv, b_convs, bufA, N);

  // convs 1,2
  for (int i = 1; i < 3; ++i) {
    colstats_kernel<<<CS_BLOCKS, 256, 0, stream>>>(bufA, N, stpX);
    fold256_kernel<<<64, 256, 0, stream>>>(stpX, CS_BLOCKS, W_convs + (size_t)i * H * H,
                                           nullptr, invN, WtB, cfB);
    gemm_kernel<<<gG, 256, 0, stream>>>(bufA, WtB, cfB, bufB, N, 0);
    agg_kernel<<<gAgg, 256, 0, stream>>>(bufB, csr_src, wn, off, dinv,
                                         b_convs + (size_t)i * H, bufA, N);
  }

  // attention
  natt_kernel<<<gN, 256, 0, stream>>>(bufA, N, W_na, b_na, W_ea, na01, p01, q01);
  eatt_xpre_kernel<<<gE + CS_BLOCKS, 256, 0, stream>>>(row, col, E, p01, q01, b_ea,
                                                       slot_of, att0s, degc, gE,
                                                       bufA, na01, n4, stpPre);
  wa2_fold2_kernel<<<gE + 128, 256, 0, stream>>>(csr_src, att0s, deg, degc, na01,
                                                 wfa, wfr, E, gE, stpPre, W_ctx,
                                                 W_obj, invN, Wt2, cf2);
  aggdual_kernel<<<gAgg, 256, 0, stream>>>(bufA, csr_src, wfa, wfr, off, deg, degc,
                                           na01, bufC, bufD, sumw_c, sumw_o, N);
  gemm2sw_kernel<<<2 * gG, 256, 0, stream>>>(bufC, bufD, Wt2, cf2, b_ctx, b_obj,
                                             sumw_c, sumw_o, N, gG, stpG);
  // xc=bufC, xo=bufD; stats in stpG[0..2*gG)

  // h_co = xc[perm] + xo (+stats)
  permadd_stats_kernel<<<CS_BLOCKS, 256, 0, stream>>>(bufC, bufD, perm, bufA, n4, stpCO);

  // 3 readouts, batched, in-place
  fold3_kernel<<<192, 256, 0, stream>>>(stpG, gG, stpG + (size_t)gG * 256, gG,
                                        stpCO, CS_BLOCKS, W_fc1, b_fc1, invN, Wt3, cf3);
  gemm3_kernel<<<3 * gG, 256, 0, stream>>>(bufC, bufD, bufA, Wt3, cf3, N, gG, stpG);
  fold10x3_kernel<<<3 * NCLS, 128, 0, stream>>>(stpG, gG, W_fc2, b_fc2, invN, W2f, c2f);
  fc2x3_kernel<<<3 * gN, 256, 0, stream>>>(bufC, bufD, bufA, W2f, c2f, out, N, gN);
}

// Round 13
// 833.691 us; speedup vs baseline: 1.1635x; 1.0849x over previous
//
#include <hip/hip_runtime.h>
#include <math.h>

#define H 128
#define NCLS 10
#define EPS 1e-5f
#define BN_BETA 1e-4f
#define CS_BLOCKS 256

typedef unsigned short u16;
typedef unsigned int u32;
typedef __attribute__((ext_vector_type(8))) short short8;
typedef __attribute__((ext_vector_type(4))) float floatx4;

// ---- bf16 helpers (bit ops; RNE) ----
__device__ inline float bflo(u32 u) { union { u32 i; float f; } a; a.i = u << 16; return a.f; }
__device__ inline float bfhi(u32 u) { union { u32 i; float f; } a; a.i = u & 0xffff0000u; return a.f; }
__device__ inline u16 f2bf(float f) {
  union { float f; u32 i; } v; v.f = f;
  return (u16)((v.i + 0x7fff + ((v.i >> 16) & 1)) >> 16);
}
__device__ inline u32 pack2(float a, float b) { return (u32)f2bf(a) | ((u32)f2bf(b) << 16); }

// ---- latency-tolerant partial-row reduction: 8 independent streams ----------
__device__ inline void reduce_partials(const float* __restrict__ P, int nb, int stride,
                                       int off0, int f, float* su_out, float* sq_out) {
  float su[8] = {0, 0, 0, 0, 0, 0, 0, 0}, sq[8] = {0, 0, 0, 0, 0, 0, 0, 0};
  int b = 0;
  for (; b + 8 <= nb; b += 8) {
#pragma unroll
    for (int u = 0; u < 8; u++) {
      const float* p = P + (size_t)(b + u) * stride + off0;
      su[u] += p[f];
      sq[u] += p[128 + f];
    }
  }
  for (; b < nb; b++) {
    const float* p = P + (size_t)b * stride + off0;
    su[0] += p[f];
    sq[0] += p[128 + f];
  }
  *su_out = ((su[0] + su[1]) + (su[2] + su[3])) + ((su[4] + su[5]) + (su[6] + su[7]));
  *sq_out = ((sq[0] + sq[1]) + (sq[2] + sq[3])) + ((sq[4] + sq[5]) + (sq[6] + sq[7]));
}

// ---- fold body for 256 threads: 2 output columns per block -----------------
__device__ inline void fold256_body(const float* P, int nb, int stride, int off0,
                                    const float* W, const float* bias, float invN,
                                    int kp, u16* Wt, float* cf) {
  int f = threadIdx.x & 127;
  int half = threadIdx.x >> 7;
  int k = kp * 2 + half;
  float su, sq;
  reduce_partials(P, nb, stride, off0, f, &su, &sq);
  float mu = su * invN;
  float var = sq * invN - mu * mu;
  float s = 1.0f / sqrtf(fmaxf(var, 0.f) + EPS);
  float w = W[(size_t)f * H + k];
  Wt[(size_t)k * H + f] = f2bf(s * w);
  __shared__ float red[2][128];
  red[half][f] = (BN_BETA - mu * s) * w;
  __syncthreads();
  for (int o = 64; o > 0; o >>= 1) {
    if (f < o) red[half][f] += red[half][f + o];
    __syncthreads();
  }
  if (f == 0) cf[k] = red[half][0] + (bias ? bias[k] : 0.f);
}

// ================= small device bodies ======================================
// hist with rank capture: rank = old count (free slot assignment)
__device__ inline void hist_body(const int* __restrict__ row, const int* __restrict__ col,
                                 int E, int* cnt_in, int* cnt_out,
                                 int* rank_in, int* rank_out, int blk) {
  int e = blk * 256 + threadIdx.x;
  if (e < E) {
    rank_in[e] = atomicAdd(&cnt_in[col[e]], 1);
    rank_out[e] = atomicAdd(&cnt_out[row[e]], 1);
  }
}

__device__ inline void xstats_body(const float* __restrict__ x, int n4,
                                   float* __restrict__ stp, int blk) {
  int tid = threadIdx.x;
  int lane = tid & 63, wave = tid >> 6;
  float s[4] = {0, 0, 0, 0}, q[4] = {0, 0, 0, 0};
  int step = CS_BLOCKS * 256;
  for (int i = blk * 256 + tid; i < n4; i += step) {
    float4 v = ((const float4*)x)[i];
    s[0] += v.x; q[0] += v.x * v.x; s[1] += v.y; q[1] += v.y * v.y;
    s[2] += v.z; q[2] += v.z * v.z; s[3] += v.w; q[3] += v.w * v.w;
  }
#pragma unroll
  for (int k = 0; k < 4; k++) { s[k] += __shfl_xor(s[k], 32); q[k] += __shfl_xor(q[k], 32); }
  __shared__ float smx[4][256];
  int col = (lane & 31) * 4;
  if (lane < 32) {
#pragma unroll
    for (int k = 0; k < 4; k++) { smx[wave][col + k] = s[k]; smx[wave][128 + col + k] = q[k]; }
  }
  __syncthreads();
  stp[(size_t)blk * 256 + tid] = smx[0][tid] + smx[1][tid] + smx[2][tid] + smx[3][tid];
}

// scanA: block sums of cnt_in and cnt_out + dinv from out-degree
__device__ inline void scanA_body(const int* cnt_in, const int* cnt_out, int N,
                                  int* partial_in, int* partial_out, float* dinv, int blk) {
  int i = blk * 256 + threadIdx.x;
  int vo = (i < N) ? cnt_out[i] : 0;
  if (i < N) dinv[i] = 1.0f / sqrtf((float)vo + 1.0f);
  __shared__ int sdA[256];
  sdA[threadIdx.x] = (i < N) ? cnt_in[i] : 0;
  __syncthreads();
  for (int o = 128; o > 0; o >>= 1) {
    if (threadIdx.x < o) sdA[threadIdx.x] += sdA[threadIdx.x + o];
    __syncthreads();
  }
  if (threadIdx.x == 0) partial_in[blk] = sdA[0];
  __syncthreads();
  sdA[threadIdx.x] = vo;
  __syncthreads();
  for (int o = 128; o > 0; o >>= 1) {
    if (threadIdx.x < o) sdA[threadIdx.x] += sdA[threadIdx.x + o];
    __syncthreads();
  }
  if (threadIdx.x == 0) partial_out[blk] = sdA[0];
}

__device__ inline void scanB1(const int* partial, int nb, int* blockoff) {
  __shared__ int sdB[256];
  int t = threadIdx.x;
  int v = (t < nb) ? partial[t] : 0;
  sdB[t] = v;
  __syncthreads();
  for (int o = 1; o < 256; o <<= 1) {
    int x = (t >= o) ? sdB[t - o] : 0;
    __syncthreads();
    sdB[t] += x;
    __syncthreads();
  }
  blockoff[t] = sdB[t] - v;
  __syncthreads();
}

__device__ inline void scanC1(const int* cnt, int N, const int* blockoff,
                              int* off, int E, int blk) {
  __shared__ int sdC[256];
  int t = threadIdx.x;
  int i = blk * 256 + t;
  int v = (i < N) ? cnt[i] : 0;
  sdC[t] = v;
  __syncthreads();
  for (int o = 1; o < 256; o <<= 1) {
    int x = (t >= o) ? sdC[t - o] : 0;
    __syncthreads();
    sdC[t] += x;
    __syncthreads();
  }
  if (i < N) off[i] = blockoff[blk] + sdC[t] - v;
  if (i == 0) off[N] = E;
  __syncthreads();
}

// non-atomic place via precomputed ranks
__device__ inline void place_body(const int* row, const int* col, int E,
                                  const int* rank_in, const int* rank_out,
                                  const int* off_in, const int* off_out,
                                  const float* dinv, int* csr_src, int* slot_in,
                                  int* sout, float* wn, int blk) {
  int e = blk * 256 + threadIdx.x;
  if (e < E) {
    int c = col[e], r = row[e];
    int si = off_in[c] + rank_in[e];
    csr_src[si] = r;
    slot_in[e] = si;
    wn[si] = dinv[r];
    sout[e] = off_out[r] + rank_out[e];
  }
}

// non-atomic eatt: scatter a0 into in-CSR and out-CSR orders
__device__ inline void eatt_body(const int* row, const int* col, int E,
                                 const float2* p01, const float2* q01,
                                 const float* b_ea, const int* slot_in,
                                 const int* sout, float* att0s, float* att_r, int blk) {
  int e = blk * 256 + threadIdx.x;
  if (e >= E) return;
  int r = row[e], c = col[e];
  float2 p = p01[r], q = q01[c];
  float l0 = p.x + q.x + b_ea[0];
  float l1 = p.y + q.y + b_ea[1];
  float a0 = 1.0f / (1.0f + expf(l1 - l0));
  att0s[slot_in[e]] = a0;
  att_r[sout[e]] = a0;
}

// degc[v] = contiguous segment sum of att_r over out-CSR
__device__ inline void degsum_body(const float* att_r, const int* off_out,
                                   float* degc, int N, int blk) {
  int v = blk * 256 + threadIdx.x;
  if (v >= N) return;
  int s0 = off_out[v], s1 = off_out[v + 1];
  float s = 0.f;
  for (int i = s0; i < s1; i++) s += att_r[i];
  degc[v] = s;
}

__device__ inline void xprestats_body(const u16* __restrict__ h,
                                      const float2* __restrict__ na01, int n4,
                                      float* __restrict__ stp, int blk) {
  int tid = threadIdx.x;
  int lane = tid & 63, wave = tid >> 6;
  float sc[4] = {0, 0, 0, 0}, qc[4] = {0, 0, 0, 0};
  float so[4] = {0, 0, 0, 0}, qo[4] = {0, 0, 0, 0};
  int step = CS_BLOCKS * 256;
  for (int i = blk * 256 + tid; i < n4; i += step) {
    int n = i >> 5;
    uint2 u = ((const uint2*)h)[i];
    float v0 = bflo(u.x), v1 = bfhi(u.x), v2 = bflo(u.y), v3 = bfhi(u.y);
    float2 ab = na01[n];
    float a = ab.x, b = ab.y;
    float c0 = v0 * a, c1 = v1 * a, c2 = v2 * a, c3 = v3 * a;
    float o0 = v0 * b, o1 = v1 * b, o2 = v2 * b, o3 = v3 * b;
    sc[0] += c0; qc[0] += c0 * c0; sc[1] += c1; qc[1] += c1 * c1;
    sc[2] += c2; qc[2] += c2 * c2; sc[3] += c3; qc[3] += c3 * c3;
    so[0] += o0; qo[0] += o0 * o0; so[1] += o1; qo[1] += o1 * o1;
    so[2] += o2; qo[2] += o2 * o2; so[3] += o3; qo[3] += o3 * o3;
  }
#pragma unroll
  for (int k = 0; k < 4; k++) {
    sc[k] += __shfl_xor(sc[k], 32); qc[k] += __shfl_xor(qc[k], 32);
    so[k] += __shfl_xor(so[k], 32); qo[k] += __shfl_xor(qo[k], 32);
  }
  __shared__ float smp[4][512];
  int col = (lane & 31) * 4;
  if (lane < 32) {
#pragma unroll
    for (int k = 0; k < 4; k++) {
      smp[wave][col + k] = sc[k];
      smp[wave][128 + col + k] = qc[k];
      smp[wave][256 + col + k] = so[k];
      smp[wave][384 + col + k] = qo[k];
    }
  }
  __syncthreads();
  float r0 = smp[0][tid] + smp[1][tid] + smp[2][tid] + smp[3][tid];
  float r1 = smp[0][256 + tid] + smp[1][256 + tid] + smp[2][256 + tid] + smp[3][256 + tid];
  stp[(size_t)blk * 512 + tid] = r0;
  stp[(size_t)blk * 512 + 256 + tid] = r1;
}

// ================= bf16 MFMA GEMM core ======================================
__device__ inline void gemm_core(const u16* A, const float* Afp, const u16* Bt,
                                 const float* cf, const float* b2, const float* sumw,
                                 u16* C, int N, int relu, int blk, float* stp) {
  int tid = threadIdx.x;
  int wave = tid >> 6, lane = tid & 63;
  int l15 = lane & 15, quad = lane >> 4;
  int row0 = (blk * 4 + wave) * 16;
  if (row0 >= N && !stp) return;
  int arow = row0 + l15;
  short8 a[4];
  short8 z8 = {0, 0, 0, 0, 0, 0, 0, 0};
  if (Afp) {
#pragma unroll
    for (int k4 = 0; k4 < 4; k4++) {
      if (arow < N) {
        const float* p = Afp + (size_t)arow * H + k4 * 32 + quad * 8;
        float4 f0 = *(const float4*)p;
        float4 f1 = *(const float4*)(p + 4);
        union { short8 s8; u32 u[4]; } cv;
        cv.u[0] = pack2(f0.x, f0.y); cv.u[1] = pack2(f0.z, f0.w);
        cv.u[2] = pack2(f1.x, f1.y); cv.u[3] = pack2(f1.z, f1.w);
        a[k4] = cv.s8;
      } else a[k4] = z8;
    }
  } else {
#pragma unroll
    for (int k4 = 0; k4 < 4; k4++)
      a[k4] = (arow < N) ? *(const short8*)(A + (size_t)arow * H + k4 * 32 + quad * 8) : z8;
  }
  float srow[4];
  if (sumw) {
#pragma unroll
    for (int r = 0; r < 4; r++) {
      int row = row0 + quad * 4 + r;
      srow[r] = (row < N) ? sumw[row] : 0.f;
    }
  }
  float ps[8], pq[8];
#pragma unroll
  for (int nt = 0; nt < 8; nt++) {
    floatx4 acc = {0.f, 0.f, 0.f, 0.f};
    const u16* bp = Bt + (size_t)(nt * 16 + l15) * H + quad * 8;
#pragma unroll
    for (int k4 = 0; k4 < 4; k4++) {
      short8 b = *(const short8*)(bp + k4 * 32);
      acc = __builtin_amdgcn_mfma_f32_16x16x32_bf16(a[k4], b, acc, 0, 0, 0);
    }
    int col = nt * 16 + l15;
    float base = cf[col];
    float bb = b2 ? b2[col] : 0.f;
    float s_ = 0.f, q_ = 0.f;
#pragma unroll
    for (int r = 0; r < 4; r++) {
      int row = row0 + quad * 4 + r;
      if (row < N) {
        float v = acc[r] + (sumw ? srow[r] * base + bb : base);
        if (relu) v = fmaxf(v, 0.f);
        s_ += v; q_ += v * v;
        C[(size_t)row * H + col] = f2bf(v);
      }
    }
    ps[nt] = s_; pq[nt] = q_;
  }
  if (stp) {
    __shared__ float sred[4][256];
#pragma unroll
    for (int nt = 0; nt < 8; nt++) {
      ps[nt] += __shfl_xor(ps[nt], 16); ps[nt] += __shfl_xor(ps[nt], 32);
      pq[nt] += __shfl_xor(pq[nt], 16); pq[nt] += __shfl_xor(pq[nt], 32);
    }
    if (quad == 0) {
#pragma unroll
      for (int nt = 0; nt < 8; nt++) {
        sred[wave][nt * 16 + l15] = ps[nt];
        sred[wave][128 + nt * 16 + l15] = pq[nt];
      }
    }
    __syncthreads();
    stp[(size_t)blk * 256 + tid] =
        sred[0][tid] + sred[1][tid] + sred[2][tid] + sred[3][tid];
  }
}

// ================= merged kernels ===========================================
__global__ __launch_bounds__(256) void hist_xstats_kernel(
    const int* row, const int* col, int E, int* cnt_in, int* cnt_out,
    int* rank_in, int* rank_out, int gE, const float* x, int n4, float* stpX) {
  if ((int)blockIdx.x < gE)
    hist_body(row, col, E, cnt_in, cnt_out, rank_in, rank_out, blockIdx.x);
  else
    xstats_body(x, n4, stpX, blockIdx.x - gE);
}

__global__ __launch_bounds__(256) void scanA_fold_kernel(
    const int* cnt_in, const int* cnt_out, int N, int* partial_in, int* partial_out,
    float* dinv, int SB, const float* stpX, const float* W_feat, const float* b_feat,
    float invN, u16* WtA, float* cfA) {
  if ((int)blockIdx.x < SB)
    scanA_body(cnt_in, cnt_out, N, partial_in, partial_out, dinv, blockIdx.x);
  else
    fold256_body(stpX, CS_BLOCKS, 256, 0, W_feat, b_feat, invN, blockIdx.x - SB, WtA, cfA);
}

__global__ __launch_bounds__(256) void scanB_gemmx_kernel(
    const int* partial_in, const int* partial_out, int nb, int* blockoff_in,
    int* blockoff_out, const float* x, const u16* WtA, const float* cfA, u16* C,
    int N, float* stpG) {
  if (blockIdx.x == 0) {
    scanB1(partial_in, nb, blockoff_in);
    scanB1(partial_out, nb, blockoff_out);
  } else {
    gemm_core(nullptr, x, WtA, cfA, nullptr, nullptr, C, N, 1, blockIdx.x - 1, stpG);
  }
}

__global__ __launch_bounds__(256) void scanC_fold_kernel(
    const int* cnt_in, const int* cnt_out, int N, const int* blockoff_in,
    const int* blockoff_out, int* off_in, int* off_out, int E, int SB,
    const float* stpG, int nbG, const float* Wc, float invN, u16* WtB, float* cfB) {
  if ((int)blockIdx.x < SB) {
    scanC1(cnt_in, N, blockoff_in, off_in, E, blockIdx.x);
    scanC1(cnt_out, N, blockoff_out, off_out, E, blockIdx.x);
  } else {
    fold256_body(stpG, nbG, 256, 0, Wc, nullptr, invN, blockIdx.x - SB, WtB, cfB);
  }
}

__global__ __launch_bounds__(256) void place_gemm_kernel(
    const int* row, const int* col, int E, const int* rank_in, const int* rank_out,
    const int* off_in, const int* off_out, const float* dinv, int* csr_src,
    int* slot_in, int* sout, float* wn, int gE,
    const u16* A, const u16* WtB, const float* cfB, u16* C, int N) {
  if ((int)blockIdx.x < gE)
    place_body(row, col, E, rank_in, rank_out, off_in, off_out, dinv, csr_src,
               slot_in, sout, wn, blockIdx.x);
  else
    gemm_core(A, nullptr, WtB, cfB, nullptr, nullptr, C, N, 0, blockIdx.x - gE, nullptr);
}

__global__ __launch_bounds__(256) void eatt_xpre_kernel(
    const int* row, const int* col, int E, const float2* p01, const float2* q01,
    const float* b_ea, const int* slot_in, const int* sout, float* att0s,
    float* att_r, int gE, const u16* h, const float2* na01, int n4, float* stpPre) {
  if ((int)blockIdx.x < gE)
    eatt_body(row, col, E, p01, q01, b_ea, slot_in, sout, att0s, att_r, blockIdx.x);
  else
    xprestats_body(h, na01, n4, stpPre, blockIdx.x - gE);
}

__global__ __launch_bounds__(256) void degsum_fold2_kernel(
    const float* att_r, const int* off_out, float* degc, int N, int gN,
    const float* stpPre, const float* W_ctx, const float* W_obj, float invN,
    u16* Wt2, float* cf2) {
  if ((int)blockIdx.x < gN)
    degsum_body(att_r, off_out, degc, N, blockIdx.x);
  else {
    int b = blockIdx.x - gN;  // 0..127
    int j = b >> 6, kp = b & 63;
    fold256_body(stpPre, CS_BLOCKS, 512, j * 256, j ? W_obj : W_ctx, nullptr, invN, kp,
                 Wt2 + (size_t)j * H * H, cf2 + j * H);
  }
}

__global__ __launch_bounds__(256) void permadd_fold31_kernel(
    const u16* xc, const u16* xo, const int* perm, u16* outb, int n4, float* stpCO,
    const float* stpG, int nbG, const float* W_fc1, const float* b_fc1, float invN,
    u16* Wt3, float* cf3) {
  int tid = threadIdx.x;
  if ((int)blockIdx.x >= CS_BLOCKS) {
    int b = blockIdx.x - CS_BLOCKS;  // 0..127 -> heads 0,1
    int j = b >> 6, kp = b & 63;
    fold256_body(stpG + (size_t)j * nbG * 256, nbG, 256, 0, W_fc1 + (size_t)j * H * H,
                 b_fc1 + j * H, invN, kp, Wt3 + (size_t)j * H * H, cf3 + j * H);
    return;
  }
  int blk = blockIdx.x;
  int lane = tid & 63, wave = tid >> 6;
  float s[4] = {0, 0, 0, 0}, q[4] = {0, 0, 0, 0};
  int step = CS_BLOCKS * 256;
  for (int i = blk * 256 + tid; i < n4; i += step) {
    int n = i >> 5, k = i & 31;
    int p = perm[n];
    uint2 a = ((const uint2*)xc)[(size_t)p * 32 + k];
    uint2 b = ((const uint2*)xo)[i];
    float f0 = bflo(a.x) + bflo(b.x), f1 = bfhi(a.x) + bfhi(b.x);
    float f2 = bflo(a.y) + bflo(b.y), f3 = bfhi(a.y) + bfhi(b.y);
    ((uint2*)outb)[i] = make_uint2(pack2(f0, f1), pack2(f2, f3));
    s[0] += f0; q[0] += f0 * f0; s[1] += f1; q[1] += f1 * f1;
    s[2] += f2; q[2] += f2 * f2; s[3] += f3; q[3] += f3 * f3;
  }
#pragma unroll
  for (int k = 0; k < 4; k++) { s[k] += __shfl_xor(s[k], 32); q[k] += __shfl_xor(q[k], 32); }
  __shared__ float smq[4][256];
  int col = (lane & 31) * 4;
  if (lane < 32) {
#pragma unroll
    for (int k = 0; k < 4; k++) { smq[wave][col + k] = s[k]; smq[wave][128 + col + k] = q[k]; }
  }
  __syncthreads();
  stpCO[(size_t)blk * 256 + tid] = smq[0][tid] + smq[1][tid] + smq[2][tid] + smq[3][tid];
}

// ================= standalone kernels =======================================
__global__ __launch_bounds__(256) void fold256_kernel(
    const float* P, int nb, const float* W, const float* bias, float invN,
    u16* Wt, float* cf) {
  fold256_body(P, nb, 256, 0, W, bias, invN, blockIdx.x, Wt, cf);
}

__global__ __launch_bounds__(128) void fold10x3_kernel(
    const float* stpZ, int nb, const float* W_fc2, const float* b_fc2, float invN,
    float* W2f, float* c2f) {
  int j = blockIdx.x / NCLS, k = blockIdx.x % NCLS;
  const float* P = stpZ + (size_t)j * nb * 256;
  int f = threadIdx.x;
  float su, sq;
  reduce_partials(P, nb, 256, 0, f, &su, &sq);
  float mu = su * invN;
  float var = sq * invN - mu * mu;
  float s = 1.0f / sqrtf(fmaxf(var, 0.f) + EPS);
  float w = W_fc2[(size_t)j * H * NCLS + (size_t)f * NCLS + k];
  W2f[(size_t)j * H * NCLS + (size_t)f * NCLS + k] = s * w;
  __shared__ float red1[H];
  red1[f] = (BN_BETA - mu * s) * w;
  __syncthreads();
  for (int o = 64; o > 0; o >>= 1) {
    if (f < o) red1[f] += red1[f + o];
    __syncthreads();
  }
  if (f == 0) c2f[j * 16 + k] = red1[0] + b_fc2[j * NCLS + k];
}

__global__ __launch_bounds__(256) void gemm_kernel(
    const u16* A, const u16* Bt, const float* cf, u16* C, int N, int relu) {
  gemm_core(A, nullptr, Bt, cf, nullptr, nullptr, C, N, relu, blockIdx.x, nullptr);
}

__global__ __launch_bounds__(256) void gemm2sw_kernel(
    u16* B0, u16* B1, const u16* Wt2, const float* cf2,
    const float* b0, const float* b1, const float* sw0, const float* sw1,
    int N, int gG, float* stp) {
  int j = blockIdx.x / gG, blk = blockIdx.x % gG;
  u16* Z = j ? B1 : B0;
  gemm_core(Z, nullptr, Wt2 + (size_t)j * H * H, cf2 + j * H, j ? b1 : b0,
            j ? sw1 : sw0, Z, N, 1, blk, stp + (size_t)j * gG * 256);
}

__global__ __launch_bounds__(256) void gemm3_kernel(
    u16* Z0, u16* Z1, u16* Z2, const u16* Wt3, const float* cf3,
    int N, int gG, float* stp) {
  int j = blockIdx.x / gG, blk = blockIdx.x % gG;
  u16* Z = (j == 0) ? Z0 : (j == 1) ? Z1 : Z2;
  gemm_core(Z, nullptr, Wt3 + (size_t)j * H * H, cf3 + j * H, nullptr, nullptr,
            Z, N, 1, blk, stp + (size_t)j * gG * 256);
}

__global__ __launch_bounds__(256) void colstats_kernel(
    const u16* __restrict__ X, int N, float* __restrict__ stp) {
  int tid = threadIdx.x;
  int li = tid & 15, rg = tid >> 4;
  int wave = tid >> 6, lane = tid & 63;
  const uint4* T = (const uint4*)X;
  float s[8] = {0, 0, 0, 0, 0, 0, 0, 0}, q[8] = {0, 0, 0, 0, 0, 0, 0, 0};
  for (int r = blockIdx.x * 16 + rg; r < N; r += CS_BLOCKS * 16) {
    uint4 u = T[(size_t)r * 16 + li];
    float f[8] = {bflo(u.x), bfhi(u.x), bflo(u.y), bfhi(u.y),
                  bflo(u.z), bfhi(u.z), bflo(u.w), bfhi(u.w)};
#pragma unroll
    for (int j = 0; j < 8; j++) { s[j] += f[j]; q[j] += f[j] * f[j]; }
  }
#pragma unroll
  for (int j = 0; j < 8; j++) {
    s[j] += __shfl_xor(s[j], 16); s[j] += __shfl_xor(s[j], 32);
    q[j] += __shfl_xor(q[j], 16); q[j] += __shfl_xor(q[j], 32);
  }
  __shared__ float smc[4][256];
  if ((lane & 48) == 0) {
#pragma unroll
    for (int j = 0; j < 8; j++) {
      smc[wave][li * 8 + j] = s[j];
      smc[wave][128 + li * 8 + j] = q[j];
    }
  }
  __syncthreads();
  stp[(size_t)blockIdx.x * 256 + tid] = smc[0][tid] + smc[1][tid] + smc[2][tid] + smc[3][tid];
}

// ================= aggregation ==============================================
#define ACC8(A, U, W)                                             \
  A[0] += (W) * bflo(U.x); A[1] += (W) * bfhi(U.x);               \
  A[2] += (W) * bflo(U.y); A[3] += (W) * bfhi(U.y);               \
  A[4] += (W) * bflo(U.z); A[5] += (W) * bfhi(U.z);               \
  A[6] += (W) * bflo(U.w); A[7] += (W) * bfhi(U.w);

__global__ __launch_bounds__(256) void agg_kernel(
    const u16* __restrict__ t, const int* __restrict__ csr_src,
    const float* __restrict__ wseg, const int* __restrict__ off,
    const float* __restrict__ dinv, const float* __restrict__ bias,
    u16* __restrict__ out, int N) {
  int v = blockIdx.x * 4 + (threadIdx.x >> 6);
  if (v >= N) return;
  int lane = threadIdx.x & 63;
  int g = lane >> 4, li = lane & 15;
  const uint4* T = (const uint4*)t;
  float dv = dinv[v];
  float acc[8] = {0.f, 0.f, 0.f, 0.f, 0.f, 0.f, 0.f, 0.f};
  if (g == 0) {
    uint4 u = T[(size_t)v * 16 + li];
    float w0 = dv * dv;
    ACC8(acc, u, w0)
  }
  int s0 = off[v], s1 = off[v + 1];
  for (int s = s0; s < s1; s += 32) {
    int ix[8]; float wv[8];
#pragma unroll
    for (int u = 0; u < 8; u++) {
      int e = s + g + u * 4;
      bool ok = e < s1;
      int e2 = ok ? e : s0;
      ix[u] = csr_src[e2];
      wv[u] = ok ? wseg[e2] : 0.f;
    }
    uint4 uu[8];
#pragma unroll
    for (int u = 0; u < 8; u++) uu[u] = T[(size_t)ix[u] * 16 + li];
#pragma unroll
    for (int u = 0; u < 8; u++) { float w = wv[u] * dv; ACC8(acc, uu[u], w) }
  }
#pragma unroll
  for (int j = 0; j < 8; j++) {
    acc[j] += __shfl_xor(acc[j], 16);
    acc[j] += __shfl_xor(acc[j], 32);
  }
  if (g == 0) {
    float o[8];
#pragma unroll
    for (int j = 0; j < 8; j++) o[j] = fmaxf(acc[j] + bias[li * 8 + j], 0.f);
    uint4 w4;
    w4.x = pack2(o[0], o[1]); w4.y = pack2(o[2], o[3]);
    w4.z = pack2(o[4], o[5]); w4.w = pack2(o[6], o[7]);
    ((uint4*)out)[(size_t)v * 16 + li] = w4;
  }
}

// dual aggregation; edge weights computed inline from att0s/na01/degrees
__global__ __launch_bounds__(256) void aggdual_kernel(
    const u16* __restrict__ h, const int* __restrict__ csr_src,
    const float* __restrict__ att0s, const int* __restrict__ cnt_out,
    const float* __restrict__ degc, const float2* __restrict__ na01,
    const int* __restrict__ off,
    u16* __restrict__ gc, u16* __restrict__ go,
    float* __restrict__ sumw_c, float* __restrict__ sumw_o, int N) {
  int v = blockIdx.x * 4 + (threadIdx.x >> 6);
  if (v >= N) return;
  int lane = threadIdx.x & 63;
  int g = lane >> 4, li = lane & 15;
  const uint4* T = (const uint4*)h;
  float dgc = degc[v];
  float dvc = 1.0f / sqrtf(dgc + 1.0f);
  float dvo = 1.0f / sqrtf((float)cnt_out[v] - dgc + 1.0f);
  float ac[8] = {0.f, 0.f, 0.f, 0.f, 0.f, 0.f, 0.f, 0.f};
  float ao[8] = {0.f, 0.f, 0.f, 0.f, 0.f, 0.f, 0.f, 0.f};
  float swc = 0.f, swo = 0.f;
  if (g == 0) {
    uint4 u = T[(size_t)v * 16 + li];
    float2 na = na01[v];
    float wc = dvc * dvc, wo = dvo * dvo;
    float wch = wc * na.x, woh = wo * na.y;
    ACC8(ac, u, wch)
    ACC8(ao, u, woh)
  }
  int s0 = off[v], s1 = off[v + 1];
  for (int s = s0; s < s1; s += 16) {
    int ix[4]; float a0v[4];
#pragma unroll
    for (int u = 0; u < 4; u++) {
      int e = s + g + u * 4;
      bool ok = e < s1;
      int e2 = ok ? e : s0;
      ix[u] = csr_src[e2];
      a0v[u] = ok ? att0s[e2] : 0.f;  // a0=0 -> r0=0 and r1=(1-0)*...; must mask r1 too
      if (!ok) a0v[u] = -1.f;         // sentinel: both weights zero
    }
    uint4 uu[4];
    float2 nav[4];
    float dS[4], dC[4];
#pragma unroll
    for (int u = 0; u < 4; u++) {
      int sidx = ix[u];
      uu[u] = T[(size_t)sidx * 16 + li];
      nav[u] = na01[sidx];
      dS[u] = (float)cnt_out[sidx];
      dC[u] = degc[sidx];
    }
#pragma unroll
    for (int u = 0; u < 4; u++) {
      float a0 = a0v[u];
      bool ok = a0 >= 0.f;
      float r0 = ok ? a0 / sqrtf(dC[u] + 1.0f) : 0.f;
      float r1 = ok ? (1.0f - a0) / sqrtf(dS[u] - dC[u] + 1.0f) : 0.f;
      float wc = r0 * nav[u].x * dvc; ACC8(ac, uu[u], wc)
      float wo = r1 * nav[u].y * dvo; ACC8(ao, uu[u], wo)
      swc += r0; swo += r1;
    }
  }
#pragma unroll
  for (int j = 0; j < 8; j++) {
    ac[j] += __shfl_xor(ac[j], 16); ac[j] += __shfl_xor(ac[j], 32);
    ao[j] += __shfl_xor(ao[j], 16); ao[j] += __shfl_xor(ao[j], 32);
  }
  swc += __shfl_xor(swc, 16); swc += __shfl_xor(swc, 32);
  swo += __shfl_xor(swo, 16); swo += __shfl_xor(swo, 32);
  if (g == 0) {
    uint4 wc4, wo4;
    wc4.x = pack2(ac[0], ac[1]); wc4.y = pack2(ac[2], ac[3]);
    wc4.z = pack2(ac[4], ac[5]); wc4.w = pack2(ac[6], ac[7]);
    wo4.x = pack2(ao[0], ao[1]); wo4.y = pack2(ao[2], ao[3]);
    wo4.z = pack2(ao[4], ao[5]); wo4.w = pack2(ao[6], ao[7]);
    ((uint4*)gc)[(size_t)v * 16 + li] = wc4;
    ((uint4*)go)[(size_t)v * 16 + li] = wo4;
    if (li == 0) {
      sumw_c[v] = dvc * swc + dvc * dvc;
      sumw_o[v] = dvo * swo + dvo * dvo;
    }
  }
}

// ================= node attention + edge-att p,q factors =====================
__global__ __launch_bounds__(256) void natt_kernel(
    const u16* __restrict__ h, int N,
    const float* __restrict__ W_na, const float* __restrict__ b_na,
    const float* __restrict__ W_ea,
    float2* __restrict__ na01, float2* __restrict__ p01, float2* __restrict__ q01) {
  int n = blockIdx.x * 256 + threadIdx.x;
  if (n >= N) return;
  float sa0 = 0, sa1 = 0, sp0 = 0, sp1 = 0, sq0 = 0, sq1 = 0;
  const uint2* hr = (const uint2*)(h + (size_t)n * H);
  for (int c = 0; c < 32; c++) {
    uint2 u = hr[c];
    float v0 = bflo(u.x), v1 = bfhi(u.x), v2 = bflo(u.y), v3 = bfhi(u.y);
    int k = c * 4;
    sa0 += v0 * W_na[k * 2] + v1 * W_na[k * 2 + 2] + v2 * W_na[k * 2 + 4] + v3 * W_na[k * 2 + 6];
    sa1 += v0 * W_na[k * 2 + 1] + v1 * W_na[k * 2 + 3] + v2 * W_na[k * 2 + 5] + v3 * W_na[k * 2 + 7];
    sp0 += v0 * W_ea[k * 2] + v1 * W_ea[k * 2 + 2] + v2 * W_ea[k * 2 + 4] + v3 * W_ea[k * 2 + 6];
    sp1 += v0 * W_ea[k * 2 + 1] + v1 * W_ea[k * 2 + 3] + v2 * W_ea[k * 2 + 5] + v3 * W_ea[k * 2 + 7];
    sq0 += v0 * W_ea[(H + k) * 2] + v1 * W_ea[(H + k) * 2 + 2] + v2 * W_ea[(H + k) * 2 + 4] + v3 * W_ea[(H + k) * 2 + 6];
    sq1 += v0 * W_ea[(H + k) * 2 + 1] + v1 * W_ea[(H + k) * 2 + 3] + v2 * W_ea[(H + k) * 2 + 5] + v3 * W_ea[(H + k) * 2 + 7];
  }
  sa0 += b_na[0]; sa1 += b_na[1];
  float m = fmaxf(sa0, sa1);
  float e0 = expf(sa0 - m), e1 = expf(sa1 - m);
  float inv = 1.f / (e0 + e1);
  na01[n] = make_float2(e0 * inv, e1 * inv);
  p01[n] = make_float2(sp0, sp1);
  q01[n] = make_float2(sq0, sq1);
}

// ================= fc2 x3: [N,128]@[128,10] + log_softmax ====================
__global__ __launch_bounds__(256) void fc2x3_kernel(
    const u16* __restrict__ z0, const u16* __restrict__ z1, const u16* __restrict__ z2,
    const float* __restrict__ W2f, const float* __restrict__ c2f,
    float* __restrict__ outp, int N, int gN) {
  int j = blockIdx.x / gN, blk = blockIdx.x % gN;
  int n = blk * 256 + threadIdx.x;
  if (n >= N) return;
  const u16* z = (j == 0) ? z0 : (j == 1) ? z1 : z2;
  const float* W2 = W2f + (size_t)j * H * NCLS;
  const float* c2 = c2f + j * 16;
  float* op = outp + (size_t)j * N * NCLS;
  float acc[NCLS];
#pragma unroll
  for (int c = 0; c < NCLS; c++) acc[c] = c2[c];
  const uint2* zr = (const uint2*)(z + (size_t)n * H);
  for (int c4 = 0; c4 < 32; c4++) {
    uint2 u = zr[c4];
    float v[4] = {bflo(u.x), bfhi(u.x), bflo(u.y), bfhi(u.y)};
    int k = c4 * 4;
#pragma unroll
    for (int jj = 0; jj < 4; jj++)
#pragma unroll
      for (int c = 0; c < NCLS; c++) acc[c] += v[jj] * W2[(k + jj) * NCLS + c];
  }
  float m = acc[0];
#pragma unroll
  for (int c = 1; c < NCLS; c++) m = fmaxf(m, acc[c]);
  float s = 0.f;
#pragma unroll
  for (int c = 0; c < NCLS; c++) s += expf(acc[c] - m);
  float lse = logf(s) + m;
#pragma unroll
  for (int c = 0; c < NCLS; c++) op[(size_t)n * NCLS + c] = acc[c] - lse;
}

// =============================================================================
extern "C" void kernel_launch(void* const* d_in, const int* in_sizes, int n_in,
                              void* d_out, int out_size, void* d_ws, size_t ws_size,
                              hipStream_t stream) {
  const int N = in_sizes[0] / H;
  const int E = in_sizes[1] / 2;
  const float* x = (const float*)d_in[0];
  const int* ei = (const int*)d_in[1];
  const int* row = ei;
  const int* col = ei + E;
  const int* perm = (const int*)d_in[2];
  const float* W_feat = (const float*)d_in[3];
  const float* b_feat = (const float*)d_in[4];
  const float* W_convs = (const float*)d_in[5];
  const float* b_convs = (const float*)d_in[6];
  const float* W_ea = (const float*)d_in[7];
  const float* b_ea = (const float*)d_in[8];
  const float* W_na = (const float*)d_in[9];
  const float* b_na = (const float*)d_in[10];
  const float* W_ctx = (const float*)d_in[11];
  const float* b_ctx = (const float*)d_in[12];
  const float* W_obj = (const float*)d_in[13];
  const float* b_obj = (const float*)d_in[14];
  const float* W_fc1 = (const float*)d_in[15];
  const float* b_fc1 = (const float*)d_in[16];
  const float* W_fc2 = (const float*)d_in[17];
  const float* b_fc2 = (const float*)d_in[18];
  float* out = (float*)d_out;

  const int gG = (N + 63) / 64;
  const int gN = (N + 255) / 256;
  const int gE = (E + 255) / 256;
  const int SB = (N + 255) / 256;
  const int n4 = N * 32;
  const int gAgg = (N + 3) / 4;
  const float invN = 1.0f / (float)N;

  // ---------- workspace carve ----------
  char* base = (char*)d_ws;
  size_t off_b = 0;
  auto alloc = [&](size_t bytes) -> void* {
    void* p = base + off_b;
    off_b = (off_b + bytes + 255) & ~(size_t)255;
    return p;
  };
  size_t NB2 = (size_t)N * H * sizeof(u16);
  u16* bufA = (u16*)alloc(NB2);  // h chain; hco; z2
  u16* bufB = (u16*)alloc(NB2);  // conv t temp
  u16* bufC = (u16*)alloc(NB2);  // gc -> xc -> z0
  u16* bufD = (u16*)alloc(NB2);  // go -> xo -> z1
  int* cnt_in = (int*)alloc(2 * (size_t)N * 4);  // cnt_in, cnt_out (one memset)
  int* cnt_out = cnt_in + N;
  float* degc = (float*)alloc((size_t)N * 4);
  float* stpX = (float*)alloc((size_t)CS_BLOCKS * 256 * 4);
  float* stpG = (float*)alloc(3 * (size_t)gG * 256 * 4);
  float* stpPre = (float*)alloc((size_t)CS_BLOCKS * 512 * 4);
  float* stpCO = (float*)alloc((size_t)CS_BLOCKS * 256 * 4);
  int* off_in = (int*)alloc(((size_t)N + 1) * 4);
  int* off_out = (int*)alloc(((size_t)N + 1) * 4);
  float* dinv = (float*)alloc((size_t)N * 4);
  float* sumw_c = (float*)alloc((size_t)N * 4);
  float* sumw_o = (float*)alloc((size_t)N * 4);
  float2* na01 = (float2*)alloc((size_t)N * 8);
  float2* p01 = (float2*)alloc((size_t)N * 8);
  float2* q01 = (float2*)alloc((size_t)N * 8);
  int* partial_in = (int*)alloc(256 * 4);
  int* partial_out = (int*)alloc(256 * 4);
  int* blockoff_in = (int*)alloc(256 * 4);
  int* blockoff_out = (int*)alloc(256 * 4);
  u16* WtA = (u16*)alloc((size_t)H * H * 2);
  u16* WtB = (u16*)alloc((size_t)H * H * 2);
  u16* Wt2 = (u16*)alloc(2 * (size_t)H * H * 2);
  u16* Wt3 = (u16*)alloc(3 * (size_t)H * H * 2);
  float* cfA = (float*)alloc(H * 4);
  float* cfB = (float*)alloc(H * 4);
  float* cf2 = (float*)alloc(2 * H * 4);
  float* cf3 = (float*)alloc(3 * H * 4);
  float* W2f = (float*)alloc(3 * (size_t)H * NCLS * 4);
  float* c2f = (float*)alloc(3 * 16 * 4);
  int* rank_in = (int*)alloc((size_t)E * 4);
  int* rank_out = (int*)alloc((size_t)E * 4);
  int* csr_src = (int*)alloc((size_t)E * 4);
  int* slot_in = (int*)alloc((size_t)E * 4);
  int* sout = (int*)alloc((size_t)E * 4);
  float* att0s = (float*)alloc((size_t)E * 4);
  float* att_r = (float*)alloc((size_t)E * 4);
  float* wn = (float*)alloc((size_t)E * 4);

  // 1. zero histograms
  hipMemsetAsync(cnt_in, 0, 2 * (size_t)N * 4, stream);

  // 2. hist(+ranks) || xstats
  hist_xstats_kernel<<<gE + CS_BLOCKS, 256, 0, stream>>>(
      row, col, E, cnt_in, cnt_out, rank_in, rank_out, gE, x, n4, stpX);
  // 3. scanA(both + dinv) || fold(feat)
  scanA_fold_kernel<<<SB + 64, 256, 0, stream>>>(
      cnt_in, cnt_out, N, partial_in, partial_out, dinv, SB, stpX, W_feat, b_feat,
      invN, WtA, cfA);
  // 4. scanB(both) || gemm_x
  scanB_gemmx_kernel<<<1 + gG, 256, 0, stream>>>(
      partial_in, partial_out, SB, blockoff_in, blockoff_out, x, WtA, cfA, bufA, N, stpG);
  // 5. scanC(both) || fold(conv0)
  scanC_fold_kernel<<<SB + 64, 256, 0, stream>>>(
      cnt_in, cnt_out, N, blockoff_in, blockoff_out, off_in, off_out, E, SB,
      stpG, gG, W_convs, invN, WtB, cfB);
  // 6. place(non-atomic) || gemm(conv0: bufA -> bufB)
  place_gemm_kernel<<<gE + gG, 256, 0, stream>>>(
      row, col, E, rank_in, rank_out, off_in, off_out, dinv, csr_src, slot_in, sout,
      wn, gE, bufA, WtB, cfB, bufB, N);
  // 7. agg(conv0) -> h1 in bufA
  agg_kernel<<<gAgg, 256, 0, stream>>>(bufB, csr_src, wn, off_in, dinv, b_convs, bufA, N);

  // convs 1,2
  for (int i = 1; i < 3; ++i) {
    colstats_kernel<<<CS_BLOCKS, 256, 0, stream>>>(bufA, N, stpX);
    fold256_kernel<<<64, 256, 0, stream>>>(stpX, CS_BLOCKS, W_convs + (size_t)i * H * H,
                                           nullptr, invN, WtB, cfB);
    gemm_kernel<<<gG, 256, 0, stream>>>(bufA, WtB, cfB, bufB, N, 0);
    agg_kernel<<<gAgg, 256, 0, stream>>>(bufB, csr_src, wn, off_in, dinv,
                                         b_convs + (size_t)i * H, bufA, N);
  }

  // attention
  natt_kernel<<<gN, 256, 0, stream>>>(bufA, N, W_na, b_na, W_ea, na01, p01, q01);
  eatt_xpre_kernel<<<gE + CS_BLOCKS, 256, 0, stream>>>(
      row, col, E, p01, q01, b_ea, slot_in, sout, att0s, att_r, gE,
      bufA, na01, n4, stpPre);
  degsum_fold2_kernel<<<gN + 128, 256, 0, stream>>>(
      att_r, off_out, degc, N, gN, stpPre, W_ctx, W_obj, invN, Wt2, cf2);
  aggdual_kernel<<<gAgg, 256, 0, stream>>>(bufA, csr_src, att0s, cnt_out, degc, na01,
                                           off_in, bufC, bufD, sumw_c, sumw_o, N);
  gemm2sw_kernel<<<2 * gG, 256, 0, stream>>>(bufC, bufD, Wt2, cf2, b_ctx, b_obj,
                                             sumw_c, sumw_o, N, gG, stpG);
  // xc=bufC, xo=bufD; stats in stpG[0..2*gG)

  // h_co = xc[perm] + xo (+stats) || fold3 heads 0,1
  permadd_fold31_kernel<<<CS_BLOCKS + 128, 256, 0, stream>>>(
      bufC, bufD, perm, bufA, n4, stpCO, stpG, gG, W_fc1, b_fc1, invN, Wt3, cf3);
  // fold3 head 2 (stats from permadd)
  fold256_kernel<<<64, 256, 0, stream>>>(stpCO, CS_BLOCKS, W_fc1 + 2 * (size_t)H * H,
                                         b_fc1 + 2 * H, invN, Wt3 + 2 * (size_t)H * H,
                                         cf3 + 2 * H);
  gemm3_kernel<<<3 * gG, 256, 0, stream>>>(bufC, bufD, bufA, Wt3, cf3, N, gG, stpG);
  fold10x3_kernel<<<3 * NCLS, 128, 0, stream>>>(stpG, gG, W_fc2, b_fc2, invN, W2f, c2f);
  fc2x3_kernel<<<3 * gN, 256, 0, stream>>>(bufC, bufD, bufA, W2f, c2f, out, N, gN);
}